// Round 5
// baseline (1569.623 us; speedup 1.0000x reference)
//
#include <hip/hip_runtime.h>

// MPNNLSTM round 4:
//  - padded CSR (64 slots/row) direct placement -> deletes deg_cnt + 3 scan kernels
//  - dinv computed per-row from CSR; val = dinv[src]*w patched in place;
//    dinv[dst] applied analytically at aggregation
//  - k_spmm2: 4-edge-parallel ushort4 gathers, 2-deep pipeline, 2048 blocks
//  - LSTM (q-split wave-owned MFMA) unchanged from round 3

#define N_TOT 140000
#define NE    2240000
#define NODES 20000
#define TWIN  7
#define CIN   8
#define HD    64
#define OUTC  142
#define SLOTS 64          // padded CSR row capacity (max deg ~36 for Poisson(16))
#define NTILES 1250       // 20000/16 node-tiles

typedef __attribute__((ext_vector_type(8))) short short8;
typedef __attribute__((ext_vector_type(4))) float f32x4;

static __device__ __forceinline__ float fast_exp2(float x) {
  return __builtin_amdgcn_exp2f(x);
}
static __device__ __forceinline__ float fast_rcp(float x) {
  return __builtin_amdgcn_rcpf(x);
}
static __device__ __forceinline__ float sigf(float x) {
  return fast_rcp(1.0f + fast_exp2(-1.4426950408889634f * x));
}
static __device__ __forceinline__ float tanhf_(float x) {
  return 1.0f - 2.0f * fast_rcp(1.0f + fast_exp2(2.8853900817779268f * x));
}
static __device__ __forceinline__ ushort f2bf(float x) {
  union { float f; uint32_t u; } c; c.f = x;
  uint32_t r = c.u + 0x7fff + ((c.u >> 16) & 1);   // RNE
  return (ushort)(r >> 16);
}
static __device__ __forceinline__ float bf2f(ushort h) {
  union { uint32_t u; float f; } c; c.u = ((uint32_t)h) << 16; return c.f;
}

// Pack W [256][K] (row-major f32) into MFMA B-fragment order.
__global__ __launch_bounds__(256) void k_pack(const float* __restrict__ W,
                                              ushort* __restrict__ Wp, int K) {
  int idx = blockIdx.x * 256 + threadIdx.x;
  int total = (K >> 5) * 16 * 64 * 8;
  if (idx < total) {
    int j = idx & 7, lane = (idx >> 3) & 63, nt = (idx >> 9) & 15, kc = idx >> 13;
    int g = nt * 16 + (lane & 15);
    int k = kc * 32 + ((lane >> 4) << 3) + j;
    Wp[idx] = f2bf(W[g * K + k]);
  }
}

// Pack Wih1 [256][128] with per-k BN scale folded in (k<64: scale1, else scale2).
__global__ __launch_bounds__(256) void k_pack_s(const float* __restrict__ W,
                                                const float* __restrict__ scale1,
                                                const float* __restrict__ scale2,
                                                ushort* __restrict__ Wp) {
  int idx = blockIdx.x * 256 + threadIdx.x;
  if (idx < 32768) {
    int j = idx & 7, lane = (idx >> 3) & 63, nt = (idx >> 9) & 15, kc = idx >> 13;
    int g = nt * 16 + (lane & 15);
    int k = kc * 32 + ((lane >> 4) << 3) + j;
    float s = (k < HD) ? scale1[k] : scale2[k - HD];
    Wp[idx] = f2bf(W[g * 128 + k] * s);
  }
}

// biasL1[col] = bih1+bhh1 + sum_k Wih1[col][k]*shift_k   (BN shift folded)
__global__ __launch_bounds__(256) void k_bias1(const float* __restrict__ Wih1,
                                               const float* __restrict__ bih1,
                                               const float* __restrict__ bhh1,
                                               const float* __restrict__ shift1,
                                               const float* __restrict__ shift2,
                                               float* __restrict__ biasL1) {
  int col = threadIdx.x;
  float s = bih1[col] + bhh1[col];
  for (int k = 0; k < HD; ++k) s += Wih1[col * 128 + k] * shift1[k];
  for (int k = 0; k < HD; ++k) s += Wih1[col * 128 + HD + k] * shift2[k];
  biasL1[col] = s;
}

__global__ __launch_bounds__(256) void k_bsum2(const float* __restrict__ bih2,
                                               const float* __restrict__ bhh2,
                                               float* __restrict__ bsum2) {
  int t = threadIdx.x;
  bsum2[t] = bih2[t] + bhh2[t];
}

// Direct CSR placement: csr[dst*SLOTS + pos] = (src, raw w). cursor ends = deg count.
__global__ __launch_bounds__(256) void k_fill_direct(const int* __restrict__ srcI,
                                                     const int* __restrict__ dstI,
                                                     const float* __restrict__ w,
                                                     int* cursor,
                                                     int2* __restrict__ csr) {
  int e = blockIdx.x * 256 + threadIdx.x;
  if (e < NE) {
    int s = srcI[e], d = dstI[e];
    int pos = atomicAdd(&cursor[d], 1);
    if (pos < SLOTS) {
      int2 cv; cv.x = s; cv.y = __float_as_int(w[e]);
      csr[(size_t)d * SLOTS + pos] = cv;
    }
  }
}

// dinv[d] = rsqrt(1 + sum_row w). Wave per row, butterfly reduce.
__global__ __launch_bounds__(256) void k_degrow(const int* __restrict__ cursor,
                                                const int2* __restrict__ csr,
                                                float* __restrict__ dinv) {
  int wv = (blockIdx.x * 256 + threadIdx.x) >> 6;
  int lane = threadIdx.x & 63;
  int nw = (gridDim.x * 256) >> 6;
  for (int d = wv; d < N_TOT; d += nw) {
    int len = min(cursor[d], SLOTS);
    float w = (lane < len) ? __int_as_float(csr[(size_t)d * SLOTS + lane].y) : 0.f;
    #pragma unroll
    for (int m = 1; m < 64; m <<= 1) w += __shfl_xor(w, m);
    if (lane == 0) dinv[d] = rsqrtf(1.0f + w);
  }
}

// Patch csr val in place: val = w * dinv[src]  (dinv[dst] applied at aggregation)
__global__ __launch_bounds__(256) void k_finval(const int* __restrict__ cursor,
                                                const float* __restrict__ dinv,
                                                int2* __restrict__ csr) {
  int idx = blockIdx.x * 256 + threadIdx.x;
  if (idx < N_TOT * SLOTS) {
    int d = idx >> 6, s_ = idx & (SLOTS - 1);
    if (s_ < min(cursor[d], SLOTS)) {
      int2 cv = csr[idx];
      cv.y = __float_as_int(__int_as_float(cv.y) * dinv[cv.x]);
      csr[idx] = cv;
    }
  }
}

// GCN layer 1 fused: 8-dim gather-aggregate + GEMM(W1) + relu + BN stats.
// pre = di*agg + di^2*x_d  (val already holds dinv[src]*w)
__global__ __launch_bounds__(256) void k_gcn1(const float* __restrict__ x,
                                              const float* __restrict__ dinv,
                                              const int* __restrict__ cursor,
                                              const int2* __restrict__ csr,
                                              const float* __restrict__ W1,
                                              const float* __restrict__ b1,
                                              ushort* __restrict__ A1,
                                              float* gsum, float* gsq) {
  __shared__ float w1s[CIN * HD];
  __shared__ float b1s[HD];
  for (int i = threadIdx.x; i < CIN * HD; i += 256) w1s[i] = W1[i];
  if (threadIdx.x < HD) b1s[threadIdx.x] = b1[threadIdx.x];
  __syncthreads();
  int wid = (blockIdx.x * 256 + threadIdx.x) >> 6;
  int lane = threadIdx.x & 63;
  int nw = (gridDim.x * 256) >> 6;
  int e8 = lane >> 3, c8 = lane & 7;
  float s = 0.f, q = 0.f;
  for (int d = wid; d < N_TOT; d += nw) {
    const int2* row = csr + ((size_t)d << 6);
    int len = min(cursor[d], SLOTS);
    float part = 0.f;
    for (int i = e8; i < len; i += 8) {
      int2 cv = row[i];
      part += __int_as_float(cv.y) * x[(size_t)cv.x * CIN + c8];
    }
    part += __shfl_xor(part, 8);
    part += __shfl_xor(part, 16);
    part += __shfl_xor(part, 32);
    float di = dinv[d];
    float di2 = di * di;
    float xd = x[(size_t)d * CIN + c8];
    float acc = b1s[lane];
    #pragma unroll
    for (int c = 0; c < CIN; ++c) {
      float aggc = di * __shfl(part, c) + di2 * __shfl(xd, c);
      acc += aggc * w1s[c * HD + lane];
    }
    float r = fmaxf(acc, 0.f);
    A1[(size_t)d * HD + lane] = f2bf(r);
    s += r; q += r * r;
  }
  atomicAdd(&gsum[lane], s);
  atomicAdd(&gsq[lane], q);
}

__global__ __launch_bounds__(64) void k_bnfin(const float* __restrict__ gsum,
                                              const float* __restrict__ gsq,
                                              const float* __restrict__ gamma,
                                              const float* __restrict__ beta,
                                              float* __restrict__ scale,
                                              float* __restrict__ shift) {
  int j = threadIdx.x;
  if (j < HD) {
    float m = gsum[j] / (float)N_TOT;
    float v = gsq[j] / (float)N_TOT - m * m;
    float sc = gamma[j] * rsqrtf(v + 1e-5f);
    scale[j] = sc;
    shift[j] = beta[j] - m * sc;
  }
}

// Hb = bf16( BN1(A1) @ W2 ); wave per row; W2 is [k][j] layout
__global__ __launch_bounds__(256) void k_gemm_h(const ushort* __restrict__ A1,
                                                const float* __restrict__ scale,
                                                const float* __restrict__ shift,
                                                const float* __restrict__ W2,
                                                ushort* __restrict__ Hb) {
  __shared__ float w[HD * HD];
  for (int i = threadIdx.x; i < HD * HD; i += 256) w[i] = W2[i];
  __syncthreads();
  int wid = (blockIdx.x * 256 + threadIdx.x) >> 6;
  int lane = threadIdx.x & 63;
  int nw = (gridDim.x * 256) >> 6;
  float sc = scale[lane], sh = shift[lane];
  for (int n = wid; n < N_TOT; n += nw) {
    float xj = sc * bf2f(A1[(size_t)n * HD + lane]) + sh;
    float acc = 0.f;
    #pragma unroll 8
    for (int k = 0; k < HD; ++k) acc += __shfl(xj, k, 64) * w[k * HD + lane];
    Hb[(size_t)n * HD + lane] = f2bf(acc);
  }
}

// GCN layer 2 aggregation: 4 edges in parallel per wave (16 lanes x ushort4 each),
// 2-deep pipeline. pre = di*acc + di^2*Hb_d + b2; relu; bf16 out; BN stats.
__global__ __launch_bounds__(256) void k_spmm2(const ushort* __restrict__ Hb,
                                               const float* __restrict__ dinv,
                                               const int* __restrict__ cursor,
                                               const int2* __restrict__ csr,
                                               const float* __restrict__ bias,
                                               ushort* __restrict__ A2,
                                               float* gsum, float* gsq) {
  int wid = (blockIdx.x * 256 + threadIdx.x) >> 6;
  int lane = threadIdx.x & 63;
  int nw = (gridDim.x * 256) >> 6;
  int eq = lane >> 4, l16 = lane & 15;
  float4 b4 = *reinterpret_cast<const float4*>(&bias[l16 * 4]);
  float s0 = 0.f, s1 = 0.f, s2 = 0.f, s3 = 0.f;
  float q0 = 0.f, q1 = 0.f, q2 = 0.f, q3 = 0.f;
  for (int d = wid; d < N_TOT; d += nw) {
    const int2* row = csr + ((size_t)d << 6);
    int len = min(cursor[d], SLOTS);
    float a0 = 0.f, a1 = 0.f, a2 = 0.f, a3 = 0.f;
    int i = eq;
    for (; i + 4 < len; i += 8) {
      int2 cvA = row[i];
      int2 cvB = row[i + 4];
      ushort4 hA = *reinterpret_cast<const ushort4*>(Hb + (((size_t)cvA.x) << 6) + (l16 << 2));
      ushort4 hB = *reinterpret_cast<const ushort4*>(Hb + (((size_t)cvB.x) << 6) + (l16 << 2));
      float vA = __int_as_float(cvA.y);
      float vB = __int_as_float(cvB.y);
      a0 += vA * bf2f(hA.x) + vB * bf2f(hB.x);
      a1 += vA * bf2f(hA.y) + vB * bf2f(hB.y);
      a2 += vA * bf2f(hA.z) + vB * bf2f(hB.z);
      a3 += vA * bf2f(hA.w) + vB * bf2f(hB.w);
    }
    if (i < len) {
      int2 cv = row[i];
      ushort4 hv = *reinterpret_cast<const ushort4*>(Hb + (((size_t)cv.x) << 6) + (l16 << 2));
      float v = __int_as_float(cv.y);
      a0 += v * bf2f(hv.x); a1 += v * bf2f(hv.y);
      a2 += v * bf2f(hv.z); a3 += v * bf2f(hv.w);
    }
    a0 += __shfl_xor(a0, 16); a0 += __shfl_xor(a0, 32);
    a1 += __shfl_xor(a1, 16); a1 += __shfl_xor(a1, 32);
    a2 += __shfl_xor(a2, 16); a2 += __shfl_xor(a2, 32);
    a3 += __shfl_xor(a3, 16); a3 += __shfl_xor(a3, 32);
    float di = dinv[d];
    float di2 = di * di;
    ushort4 hd = *reinterpret_cast<const ushort4*>(Hb + (((size_t)d) << 6) + (l16 << 2));
    float r0 = fmaxf(di * a0 + di2 * bf2f(hd.x) + b4.x, 0.f);
    float r1 = fmaxf(di * a1 + di2 * bf2f(hd.y) + b4.y, 0.f);
    float r2 = fmaxf(di * a2 + di2 * bf2f(hd.z) + b4.z, 0.f);
    float r3 = fmaxf(di * a3 + di2 * bf2f(hd.w) + b4.w, 0.f);
    if (eq == 0) {
      ushort4 st;
      st.x = f2bf(r0); st.y = f2bf(r1); st.z = f2bf(r2); st.w = f2bf(r3);
      *reinterpret_cast<ushort4*>(A2 + (((size_t)d) << 6) + (l16 << 2)) = st;
      s0 += r0; s1 += r1; s2 += r2; s3 += r3;
      q0 += r0 * r0; q1 += r1 * r1; q2 += r2 * r2; q3 += r3 * r3;
    }
  }
  if (eq == 0) {
    atomicAdd(&gsum[l16 * 4 + 0], s0); atomicAdd(&gsq[l16 * 4 + 0], q0);
    atomicAdd(&gsum[l16 * 4 + 1], s1); atomicAdd(&gsq[l16 * 4 + 1], q1);
    atomicAdd(&gsum[l16 * 4 + 2], s2); atomicAdd(&gsq[l16 * 4 + 2], q2);
    atomicAdd(&gsum[l16 * 4 + 3], s3); atomicAdd(&gsq[l16 * 4 + 3], q3);
  }
}

// ---------------------------------------------------------------------------
// Barrier-free fused 2-layer LSTM, q-split (unchanged from round 3).
// ---------------------------------------------------------------------------
__global__ __launch_bounds__(256, 4) void k_lstm4(const ushort* __restrict__ A1,
                                                  const ushort* __restrict__ A2,
                                                  const ushort* __restrict__ Wp1,
                                                  const ushort* __restrict__ Wphh1,
                                                  const ushort* __restrict__ Wpih2,
                                                  const ushort* __restrict__ Wphh2,
                                                  const float* __restrict__ biasL1,
                                                  const float* __restrict__ bsum2,
                                                  float* __restrict__ out) {
  __shared__ ushort hbuf[4][2][2][1024];   // [wave][h1|h2][parity][16x64 swizzled]
  int t = threadIdx.x;
  int wid = t >> 6, lane = t & 63;
  int tile = blockIdx.x * 4 + wid;
  if (tile >= NTILES) return;
  int g = lane >> 4, c = lane & 15;

  float c1[16], c2[16];
  #pragma unroll
  for (int i = 0; i < 16; ++i) { c1[i] = 0.f; c2[i] = 0.f; }

  int hr[2];
  #pragma unroll
  for (int kc = 0; kc < 2; ++kc)
    hr[kc] = (c * 64 + kc * 32 + g * 8) ^ ((c & 7) << 3);

  for (int step = 0; step < TWIN; ++step) {
    int pw = step & 1, pr = pw ^ 1;
    ushort* h1w = &hbuf[wid][0][pw][0];
    ushort* h1r = &hbuf[wid][0][pr][0];
    ushort* h2w = &hbuf[wid][1][pw][0];
    ushort* h2r = &hbuf[wid][1][pr][0];
    size_t nodeoff = (size_t)(step * NODES + tile * 16 + c) * HD + g * 8;
    const ushort* a1p = A1 + nodeoff;
    const ushort* a2p = A2 + nodeoff;

    // ===== layer 1 =====
    #pragma unroll 1
    for (int q = 0; q < 4; ++q) {
      f32x4 acc[4];
      #pragma unroll
      for (int gi = 0; gi < 4; ++gi) {
        float bv = biasL1[gi * 64 + q * 16 + c];
        acc[gi] = (f32x4){bv, bv, bv, bv};
      }
      #pragma unroll
      for (int kc = 0; kc < 4; ++kc) {
        const ushort* ap = (kc < 2) ? (a1p + kc * 32) : (a2p + (kc - 2) * 32);
        short8 a = *reinterpret_cast<const short8*>(ap);
        #pragma unroll
        for (int gi = 0; gi < 4; ++gi) {
          short8 b = *reinterpret_cast<const short8*>(&Wp1[((kc * 16 + gi * 4 + q) * 64 + lane) * 8]);
          acc[gi] = __builtin_amdgcn_mfma_f32_16x16x32_bf16(a, b, acc[gi], 0, 0, 0);
        }
      }
      if (step > 0) {
        #pragma unroll
        for (int kc = 0; kc < 2; ++kc) {
          short8 a = *reinterpret_cast<const short8*>(&h1r[hr[kc]]);
          #pragma unroll
          for (int gi = 0; gi < 4; ++gi) {
            short8 b = *reinterpret_cast<const short8*>(&Wphh1[((kc * 16 + gi * 4 + q) * 64 + lane) * 8]);
            acc[gi] = __builtin_amdgcn_mfma_f32_16x16x32_bf16(a, b, acc[gi], 0, 0, 0);
          }
        }
      }
      #pragma unroll
      for (int jr = 0; jr < 4; ++jr) {
        float gi_ = acc[0][jr], gf = acc[1][jr], gg = acc[2][jr], go = acc[3][jr];
        float cc = sigf(gf) * c1[q * 4 + jr] + sigf(gi_) * tanhf_(gg);
        c1[q * 4 + jr] = cc;
        float h = sigf(go) * tanhf_(cc);
        int r = g * 4 + jr, j = q * 16 + c;
        h1w[(r * 64 + j) ^ ((r & 7) << 3)] = f2bf(h);
        if (step == TWIN - 1) out[(size_t)(tile * 16 + r) * OUTC + j] = h;
      }
    }

    // ===== layer 2 =====
    #pragma unroll 1
    for (int q = 0; q < 4; ++q) {
      f32x4 acc[4];
      #pragma unroll
      for (int gi = 0; gi < 4; ++gi) {
        float bv = bsum2[gi * 64 + q * 16 + c];
        acc[gi] = (f32x4){bv, bv, bv, bv};
      }
      #pragma unroll
      for (int kc = 0; kc < 2; ++kc) {
        short8 a = *reinterpret_cast<const short8*>(&h1w[hr[kc]]);
        #pragma unroll
        for (int gi = 0; gi < 4; ++gi) {
          short8 b = *reinterpret_cast<const short8*>(&Wpih2[((kc * 16 + gi * 4 + q) * 64 + lane) * 8]);
          acc[gi] = __builtin_amdgcn_mfma_f32_16x16x32_bf16(a, b, acc[gi], 0, 0, 0);
        }
      }
      if (step > 0) {
        #pragma unroll
        for (int kc = 0; kc < 2; ++kc) {
          short8 a = *reinterpret_cast<const short8*>(&h2r[hr[kc]]);
          #pragma unroll
          for (int gi = 0; gi < 4; ++gi) {
            short8 b = *reinterpret_cast<const short8*>(&Wphh2[((kc * 16 + gi * 4 + q) * 64 + lane) * 8]);
            acc[gi] = __builtin_amdgcn_mfma_f32_16x16x32_bf16(a, b, acc[gi], 0, 0, 0);
          }
        }
      }
      #pragma unroll
      for (int jr = 0; jr < 4; ++jr) {
        float gi_ = acc[0][jr], gf = acc[1][jr], gg = acc[2][jr], go = acc[3][jr];
        float cc = sigf(gf) * c2[q * 4 + jr] + sigf(gi_) * tanhf_(gg);
        c2[q * 4 + jr] = cc;
        float h = sigf(go) * tanhf_(cc);
        int r = g * 4 + jr, j = q * 16 + c;
        h2w[(r * 64 + j) ^ ((r & 7) << 3)] = f2bf(h);
        if (step == TWIN - 1) out[(size_t)(tile * 16 + r) * OUTC + HD + j] = h;
      }
    }
  }
}

// skip connection S -> out cols 128..141
__global__ __launch_bounds__(256) void k_out_s(const float* __restrict__ x,
                                               float* __restrict__ out) {
  int idx = blockIdx.x * 256 + threadIdx.x;
  if (idx < NODES * 14) {
    int n = idx / 14, c = idx - n * 14;
    float v = (c < CIN) ? x[n * CIN + c]
                        : x[((c - (CIN - 1)) * NODES + n) * CIN + (CIN - 1)];
    out[(size_t)n * OUTC + 128 + c] = v;
  }
}

extern "C" void kernel_launch(void* const* d_in, const int* in_sizes, int n_in,
                              void* d_out, int out_size, void* d_ws, size_t ws_size,
                              hipStream_t stream) {
  const float* x      = (const float*)d_in[0];
  const int*   ei     = (const int*)d_in[1];
  const float* ew     = (const float*)d_in[2];
  const float* W1     = (const float*)d_in[3];
  const float* b1     = (const float*)d_in[4];
  const float* W2     = (const float*)d_in[5];
  const float* b2     = (const float*)d_in[6];
  const float* gamma1 = (const float*)d_in[7];
  const float* beta1  = (const float*)d_in[8];
  const float* gamma2 = (const float*)d_in[9];
  const float* beta2  = (const float*)d_in[10];
  const float* Wih1   = (const float*)d_in[11];
  const float* Whh1   = (const float*)d_in[12];
  const float* bih1   = (const float*)d_in[13];
  const float* bhh1   = (const float*)d_in[14];
  const float* Wih2   = (const float*)d_in[15];
  const float* Whh2   = (const float*)d_in[16];
  const float* bih2   = (const float*)d_in[17];
  const float* bhh2   = (const float*)d_in[18];
  const int* srcI = ei;
  const int* dstI = ei + NE;
  float* out = (float*)d_out;

  char* base = (char*)d_ws;
  size_t off = 0;
  auto alloc = [&](size_t bytes) -> void* {
    void* p = base + off;
    off = (off + bytes + 255) & ~(size_t)255;
    return p;
  };
  // small
  float* dinv   = (float*)alloc(N_TOT * 4);
  ushort* Wp1   = (ushort*)alloc(32768 * 2);   // [4kc][16nt][64][8] (BN-scaled)
  ushort* Wphh1 = (ushort*)alloc(16384 * 2);
  ushort* Wpih2 = (ushort*)alloc(16384 * 2);
  ushort* Wphh2 = (ushort*)alloc(16384 * 2);
  float* biasL1 = (float*)alloc(256 * 4);
  float* bsum2  = (float*)alloc(256 * 4);
  float* scale1 = (float*)alloc(HD * 4);
  float* shift1 = (float*)alloc(HD * 4);
  float* scale2 = (float*)alloc(HD * 4);
  float* shift2 = (float*)alloc(HD * 4);
  // zeroed-every-call region (contiguous)
  char* zstart = base + off;
  int*   cursor = (int*)alloc(N_TOT * 4);
  float* sum1   = (float*)alloc(HD * 4);
  float* sq1    = (float*)alloc(HD * 4);
  float* sum2   = (float*)alloc(HD * 4);
  float* sq2    = (float*)alloc(HD * 4);
  size_t zbytes = (size_t)((base + off) - zstart);
  // big buffers (~125 MB)
  int2*   csr = (int2*)alloc((size_t)N_TOT * SLOTS * 8);   // 71.68 MB
  ushort* Hb  = (ushort*)alloc((size_t)N_TOT * HD * 2);
  ushort* A1  = (ushort*)alloc((size_t)N_TOT * HD * 2);
  ushort* A2  = (ushort*)alloc((size_t)N_TOT * HD * 2);

  hipMemsetAsync(zstart, 0, zbytes, stream);
  k_pack<<<(16384 + 255) / 256, 256, 0, stream>>>(Whh1, Wphh1, 64);
  k_pack<<<(16384 + 255) / 256, 256, 0, stream>>>(Wih2, Wpih2, 64);
  k_pack<<<(16384 + 255) / 256, 256, 0, stream>>>(Whh2, Wphh2, 64);
  k_bsum2<<<1, 256, 0, stream>>>(bih2, bhh2, bsum2);
  k_fill_direct<<<(NE + 255) / 256, 256, 0, stream>>>(srcI, dstI, ew, cursor, csr);
  k_degrow<<<1024, 256, 0, stream>>>(cursor, csr, dinv);
  k_finval<<<(N_TOT * SLOTS + 255) / 256, 256, 0, stream>>>(cursor, dinv, csr);
  k_gcn1<<<2048, 256, 0, stream>>>(x, dinv, cursor, csr, W1, b1, A1, sum1, sq1);
  k_bnfin<<<1, 64, 0, stream>>>(sum1, sq1, gamma1, beta1, scale1, shift1);
  k_gemm_h<<<1024, 256, 0, stream>>>(A1, scale1, shift1, W2, Hb);
  k_spmm2<<<2048, 256, 0, stream>>>(Hb, dinv, cursor, csr, b2, A2, sum2, sq2);
  k_bnfin<<<1, 64, 0, stream>>>(sum2, sq2, gamma2, beta2, scale2, shift2);
  k_pack_s<<<(32768 + 255) / 256, 256, 0, stream>>>(Wih1, scale1, scale2, Wp1);
  k_bias1<<<1, 256, 0, stream>>>(Wih1, bih1, bhh1, shift1, shift2, biasL1);
  k_lstm4<<<(NTILES + 3) / 4, 256, 0, stream>>>(A1, A2, Wp1, Wphh1, Wpih2, Wphh2,
                                                biasL1, bsum2, out);
  k_out_s<<<(NODES * 14 + 255) / 256, 256, 0, stream>>>(x, out);
}

// Round 6
// 852.734 us; speedup vs baseline: 1.8407x; 1.8407x over previous
//
#include <hip/hip_runtime.h>

// MPNNLSTM round 5:
//  - k_spmm2 reverted to round-3 structure (1 edge/iter, 64-lane row gather,
//    unroll 4) on padded CSR; grid 2048
//  - k_finval deleted: dinv[src] gathered inline in k_gcn1/k_spmm2
//  - k_gemm_h -> MFMA (BN scale folded into packed W2, shift into bias row)
//  - LSTM (q-split wave-owned MFMA) unchanged

#define N_TOT 140000
#define NE    2240000
#define NODES 20000
#define TWIN  7
#define CIN   8
#define HD    64
#define OUTC  142
#define SLOTS 64          // padded CSR row capacity (max deg ~36 for Poisson(16))
#define NTILES 1250       // 20000/16 node-tiles
#define HTILES 8750       // 140000/16 row-tiles for gemm_h

typedef __attribute__((ext_vector_type(8))) short short8;
typedef __attribute__((ext_vector_type(4))) float f32x4;

static __device__ __forceinline__ float fast_exp2(float x) {
  return __builtin_amdgcn_exp2f(x);
}
static __device__ __forceinline__ float fast_rcp(float x) {
  return __builtin_amdgcn_rcpf(x);
}
static __device__ __forceinline__ float sigf(float x) {
  return fast_rcp(1.0f + fast_exp2(-1.4426950408889634f * x));
}
static __device__ __forceinline__ float tanhf_(float x) {
  return 1.0f - 2.0f * fast_rcp(1.0f + fast_exp2(2.8853900817779268f * x));
}
static __device__ __forceinline__ ushort f2bf(float x) {
  union { float f; uint32_t u; } c; c.f = x;
  uint32_t r = c.u + 0x7fff + ((c.u >> 16) & 1);   // RNE
  return (ushort)(r >> 16);
}
static __device__ __forceinline__ float bf2f(ushort h) {
  union { uint32_t u; float f; } c; c.u = ((uint32_t)h) << 16; return c.f;
}

// Pack W [256][K] (row-major f32, gate-major) into MFMA B-fragment order.
__global__ __launch_bounds__(256) void k_pack(const float* __restrict__ W,
                                              ushort* __restrict__ Wp, int K) {
  int idx = blockIdx.x * 256 + threadIdx.x;
  int total = (K >> 5) * 16 * 64 * 8;
  if (idx < total) {
    int j = idx & 7, lane = (idx >> 3) & 63, nt = (idx >> 9) & 15, kc = idx >> 13;
    int g = nt * 16 + (lane & 15);
    int k = kc * 32 + ((lane >> 4) << 3) + j;
    Wp[idx] = f2bf(W[g * K + k]);
  }
}

// Pack Wih1 [256][128] with per-k BN scale folded in (k<64: scale1, else scale2).
__global__ __launch_bounds__(256) void k_pack_s(const float* __restrict__ W,
                                                const float* __restrict__ scale1,
                                                const float* __restrict__ scale2,
                                                ushort* __restrict__ Wp) {
  int idx = blockIdx.x * 256 + threadIdx.x;
  if (idx < 32768) {
    int j = idx & 7, lane = (idx >> 3) & 63, nt = (idx >> 9) & 15, kc = idx >> 13;
    int g = nt * 16 + (lane & 15);
    int k = kc * 32 + ((lane >> 4) << 3) + j;
    float s = (k < HD) ? scale1[k] : scale2[k - HD];
    Wp[idx] = f2bf(W[g * 128 + k] * s);
  }
}

// Pack W2 [64k][64j] (reference layout [in,out]) with scale1[k] folded, B-frag order.
// Wp2[((kc*4+nt)*64+lane)*8+jj] = bf16(scale1[k] * W2[k][nt*16+(lane&15)]),
//   k = kc*32 + (lane>>4)*8 + jj
__global__ __launch_bounds__(256) void k_pack_w2(const float* __restrict__ W2,
                                                 const float* __restrict__ scale1,
                                                 ushort* __restrict__ Wp2) {
  int idx = blockIdx.x * 256 + threadIdx.x;
  if (idx < 4096) {
    int jj = idx & 7, lane = (idx >> 3) & 63, nt = (idx >> 9) & 3, kc = idx >> 11;
    int j = nt * 16 + (lane & 15);
    int k = kc * 32 + ((lane >> 4) << 3) + jj;
    Wp2[idx] = f2bf(scale1[k] * W2[k * 64 + j]);
  }
}

// c2b[j] = sum_k shift1[k] * W2[k][j]   (BN shift folded through W2)
__global__ __launch_bounds__(64) void k_hbias(const float* __restrict__ W2,
                                              const float* __restrict__ shift1,
                                              float* __restrict__ c2b) {
  int j = threadIdx.x;
  float s = 0.f;
  for (int k = 0; k < HD; ++k) s += shift1[k] * W2[k * 64 + j];
  c2b[j] = s;
}

// biasL1[col] = bih1+bhh1 + sum_k Wih1[col][k]*shift_k   (BN shift folded)
__global__ __launch_bounds__(256) void k_bias1(const float* __restrict__ Wih1,
                                               const float* __restrict__ bih1,
                                               const float* __restrict__ bhh1,
                                               const float* __restrict__ shift1,
                                               const float* __restrict__ shift2,
                                               float* __restrict__ biasL1) {
  int col = threadIdx.x;
  float s = bih1[col] + bhh1[col];
  for (int k = 0; k < HD; ++k) s += Wih1[col * 128 + k] * shift1[k];
  for (int k = 0; k < HD; ++k) s += Wih1[col * 128 + HD + k] * shift2[k];
  biasL1[col] = s;
}

__global__ __launch_bounds__(256) void k_bsum2(const float* __restrict__ bih2,
                                               const float* __restrict__ bhh2,
                                               float* __restrict__ bsum2) {
  int t = threadIdx.x;
  bsum2[t] = bih2[t] + bhh2[t];
}

// Direct CSR placement: csr[dst*SLOTS + pos] = (src, raw w).
__global__ __launch_bounds__(256) void k_fill_direct(const int* __restrict__ srcI,
                                                     const int* __restrict__ dstI,
                                                     const float* __restrict__ w,
                                                     int* cursor,
                                                     int2* __restrict__ csr) {
  int e = blockIdx.x * 256 + threadIdx.x;
  if (e < NE) {
    int s = srcI[e], d = dstI[e];
    int pos = atomicAdd(&cursor[d], 1);
    if (pos < SLOTS) {
      int2 cv; cv.x = s; cv.y = __float_as_int(w[e]);
      csr[(size_t)d * SLOTS + pos] = cv;
    }
  }
}

// dinv[d] = rsqrt(1 + sum_row w). Wave per row, butterfly reduce.
__global__ __launch_bounds__(256) void k_degrow(const int* __restrict__ cursor,
                                                const int2* __restrict__ csr,
                                                float* __restrict__ dinv) {
  int wv = (blockIdx.x * 256 + threadIdx.x) >> 6;
  int lane = threadIdx.x & 63;
  int nw = (gridDim.x * 256) >> 6;
  for (int d = wv; d < N_TOT; d += nw) {
    int len = min(cursor[d], SLOTS);
    float w = (lane < len) ? __int_as_float(csr[(size_t)d * SLOTS + lane].y) : 0.f;
    #pragma unroll
    for (int m = 1; m < 64; m <<= 1) w += __shfl_xor(w, m);
    if (lane == 0) dinv[d] = rsqrtf(1.0f + w);
  }
}

// GCN layer 1 fused: 8-dim gather-aggregate (dinv[src] inline) + GEMM(W1) + relu + BN stats.
__global__ __launch_bounds__(256) void k_gcn1(const float* __restrict__ x,
                                              const float* __restrict__ dinv,
                                              const int* __restrict__ cursor,
                                              const int2* __restrict__ csr,
                                              const float* __restrict__ W1,
                                              const float* __restrict__ b1,
                                              ushort* __restrict__ A1,
                                              float* gsum, float* gsq) {
  __shared__ float w1s[CIN * HD];
  __shared__ float b1s[HD];
  for (int i = threadIdx.x; i < CIN * HD; i += 256) w1s[i] = W1[i];
  if (threadIdx.x < HD) b1s[threadIdx.x] = b1[threadIdx.x];
  __syncthreads();
  int wid = (blockIdx.x * 256 + threadIdx.x) >> 6;
  int lane = threadIdx.x & 63;
  int nw = (gridDim.x * 256) >> 6;
  int e8 = lane >> 3, c8 = lane & 7;
  float s = 0.f, q = 0.f;
  for (int d = wid; d < N_TOT; d += nw) {
    const int2* row = csr + ((size_t)d << 6);
    int len = min(cursor[d], SLOTS);
    float part = 0.f;
    for (int i = e8; i < len; i += 8) {
      int2 cv = row[i];
      part += __int_as_float(cv.y) * dinv[cv.x] * x[(size_t)cv.x * CIN + c8];
    }
    part += __shfl_xor(part, 8);
    part += __shfl_xor(part, 16);
    part += __shfl_xor(part, 32);
    float di = dinv[d];
    float di2 = di * di;
    float xd = x[(size_t)d * CIN + c8];
    float acc = b1s[lane];
    #pragma unroll
    for (int c = 0; c < CIN; ++c) {
      float aggc = di * __shfl(part, c) + di2 * __shfl(xd, c);
      acc += aggc * w1s[c * HD + lane];
    }
    float r = fmaxf(acc, 0.f);
    A1[(size_t)d * HD + lane] = f2bf(r);
    s += r; q += r * r;
  }
  atomicAdd(&gsum[lane], s);
  atomicAdd(&gsq[lane], q);
}

__global__ __launch_bounds__(64) void k_bnfin(const float* __restrict__ gsum,
                                              const float* __restrict__ gsq,
                                              const float* __restrict__ gamma,
                                              const float* __restrict__ beta,
                                              float* __restrict__ scale,
                                              float* __restrict__ shift) {
  int j = threadIdx.x;
  if (j < HD) {
    float m = gsum[j] / (float)N_TOT;
    float v = gsq[j] / (float)N_TOT - m * m;
    float sc = gamma[j] * rsqrtf(v + 1e-5f);
    scale[j] = sc;
    shift[j] = beta[j] - m * sc;
  }
}

// Hb = bf16( BN1(A1) @ W2 ) via MFMA. Wave = 16 rows; A-frag = direct bf16 loads
// from A1 (BN folded into Wp2/c2b). 8 MFMAs per wave.
__global__ __launch_bounds__(256) void k_gemm_h2(const ushort* __restrict__ A1,
                                                 const ushort* __restrict__ Wp2,
                                                 const float* __restrict__ c2b,
                                                 ushort* __restrict__ Hb) {
  int t = threadIdx.x, wid = t >> 6, lane = t & 63;
  int tile = blockIdx.x * 4 + wid;
  if (tile >= HTILES) return;
  int g = lane >> 4, c = lane & 15;
  const ushort* ap = A1 + ((size_t)(tile * 16 + c)) * HD + g * 8;
  f32x4 acc[4];
  #pragma unroll
  for (int nt = 0; nt < 4; ++nt) {
    float bv = c2b[nt * 16 + c];
    acc[nt] = (f32x4){bv, bv, bv, bv};
  }
  #pragma unroll
  for (int kc = 0; kc < 2; ++kc) {
    short8 a = *reinterpret_cast<const short8*>(ap + kc * 32);
    #pragma unroll
    for (int nt = 0; nt < 4; ++nt) {
      short8 b = *reinterpret_cast<const short8*>(&Wp2[((kc * 4 + nt) * 64 + lane) * 8]);
      acc[nt] = __builtin_amdgcn_mfma_f32_16x16x32_bf16(a, b, acc[nt], 0, 0, 0);
    }
  }
  #pragma unroll
  for (int nt = 0; nt < 4; ++nt)
    #pragma unroll
    for (int jr = 0; jr < 4; ++jr) {
      int r = g * 4 + jr;
      Hb[((size_t)(tile * 16 + r)) * HD + nt * 16 + c] = f2bf(acc[nt][jr]);
    }
}

// GCN layer 2 aggregation (round-3 structure): wave per dst row, lane = channel,
// one edge per iteration (uniform cv + dinv loads, 128B contiguous row gather).
__global__ __launch_bounds__(256) void k_spmm2(const ushort* __restrict__ Hb,
                                               const float* __restrict__ dinv,
                                               const int* __restrict__ cursor,
                                               const int2* __restrict__ csr,
                                               const float* __restrict__ bias,
                                               ushort* __restrict__ A2,
                                               float* gsum, float* gsq) {
  int wid = (blockIdx.x * 256 + threadIdx.x) >> 6;
  int lane = threadIdx.x & 63;
  int nw = (gridDim.x * 256) >> 6;
  float b = bias[lane];
  float s = 0.f, q = 0.f;
  for (int d = wid; d < N_TOT; d += nw) {
    const int2* row = csr + ((size_t)d << 6);
    int len = min(cursor[d], SLOTS);
    float acc = 0.f;
    #pragma unroll 4
    for (int i = 0; i < len; ++i) {
      int2 cv = row[i];
      float vs = __int_as_float(cv.y) * dinv[cv.x];
      acc += vs * bf2f(Hb[(((size_t)cv.x) << 6) + lane]);
    }
    float di = dinv[d];
    float hd = bf2f(Hb[(((size_t)d) << 6) + lane]);
    float r = fmaxf(di * acc + di * di * hd + b, 0.f);
    A2[(((size_t)d) << 6) + lane] = f2bf(r);
    s += r; q += r * r;
  }
  atomicAdd(&gsum[lane], s);
  atomicAdd(&gsq[lane], q);
}

// ---------------------------------------------------------------------------
// Barrier-free fused 2-layer LSTM, q-split (unchanged).
// ---------------------------------------------------------------------------
__global__ __launch_bounds__(256, 4) void k_lstm4(const ushort* __restrict__ A1,
                                                  const ushort* __restrict__ A2,
                                                  const ushort* __restrict__ Wp1,
                                                  const ushort* __restrict__ Wphh1,
                                                  const ushort* __restrict__ Wpih2,
                                                  const ushort* __restrict__ Wphh2,
                                                  const float* __restrict__ biasL1,
                                                  const float* __restrict__ bsum2,
                                                  float* __restrict__ out) {
  __shared__ ushort hbuf[4][2][2][1024];   // [wave][h1|h2][parity][16x64 swizzled]
  int t = threadIdx.x;
  int wid = t >> 6, lane = t & 63;
  int tile = blockIdx.x * 4 + wid;
  if (tile >= NTILES) return;
  int g = lane >> 4, c = lane & 15;

  float c1[16], c2[16];
  #pragma unroll
  for (int i = 0; i < 16; ++i) { c1[i] = 0.f; c2[i] = 0.f; }

  int hr[2];
  #pragma unroll
  for (int kc = 0; kc < 2; ++kc)
    hr[kc] = (c * 64 + kc * 32 + g * 8) ^ ((c & 7) << 3);

  for (int step = 0; step < TWIN; ++step) {
    int pw = step & 1, pr = pw ^ 1;
    ushort* h1w = &hbuf[wid][0][pw][0];
    ushort* h1r = &hbuf[wid][0][pr][0];
    ushort* h2w = &hbuf[wid][1][pw][0];
    ushort* h2r = &hbuf[wid][1][pr][0];
    size_t nodeoff = (size_t)(step * NODES + tile * 16 + c) * HD + g * 8;
    const ushort* a1p = A1 + nodeoff;
    const ushort* a2p = A2 + nodeoff;

    // ===== layer 1 =====
    #pragma unroll 1
    for (int q = 0; q < 4; ++q) {
      f32x4 acc[4];
      #pragma unroll
      for (int gi = 0; gi < 4; ++gi) {
        float bv = biasL1[gi * 64 + q * 16 + c];
        acc[gi] = (f32x4){bv, bv, bv, bv};
      }
      #pragma unroll
      for (int kc = 0; kc < 4; ++kc) {
        const ushort* ap = (kc < 2) ? (a1p + kc * 32) : (a2p + (kc - 2) * 32);
        short8 a = *reinterpret_cast<const short8*>(ap);
        #pragma unroll
        for (int gi = 0; gi < 4; ++gi) {
          short8 b = *reinterpret_cast<const short8*>(&Wp1[((kc * 16 + gi * 4 + q) * 64 + lane) * 8]);
          acc[gi] = __builtin_amdgcn_mfma_f32_16x16x32_bf16(a, b, acc[gi], 0, 0, 0);
        }
      }
      if (step > 0) {
        #pragma unroll
        for (int kc = 0; kc < 2; ++kc) {
          short8 a = *reinterpret_cast<const short8*>(&h1r[hr[kc]]);
          #pragma unroll
          for (int gi = 0; gi < 4; ++gi) {
            short8 b = *reinterpret_cast<const short8*>(&Wphh1[((kc * 16 + gi * 4 + q) * 64 + lane) * 8]);
            acc[gi] = __builtin_amdgcn_mfma_f32_16x16x32_bf16(a, b, acc[gi], 0, 0, 0);
          }
        }
      }
      #pragma unroll
      for (int jr = 0; jr < 4; ++jr) {
        float gi_ = acc[0][jr], gf = acc[1][jr], gg = acc[2][jr], go = acc[3][jr];
        float cc = sigf(gf) * c1[q * 4 + jr] + sigf(gi_) * tanhf_(gg);
        c1[q * 4 + jr] = cc;
        float h = sigf(go) * tanhf_(cc);
        int r = g * 4 + jr, j = q * 16 + c;
        h1w[(r * 64 + j) ^ ((r & 7) << 3)] = f2bf(h);
        if (step == TWIN - 1) out[(size_t)(tile * 16 + r) * OUTC + j] = h;
      }
    }

    // ===== layer 2 =====
    #pragma unroll 1
    for (int q = 0; q < 4; ++q) {
      f32x4 acc[4];
      #pragma unroll
      for (int gi = 0; gi < 4; ++gi) {
        float bv = bsum2[gi * 64 + q * 16 + c];
        acc[gi] = (f32x4){bv, bv, bv, bv};
      }
      #pragma unroll
      for (int kc = 0; kc < 2; ++kc) {
        short8 a = *reinterpret_cast<const short8*>(&h1w[hr[kc]]);
        #pragma unroll
        for (int gi = 0; gi < 4; ++gi) {
          short8 b = *reinterpret_cast<const short8*>(&Wpih2[((kc * 16 + gi * 4 + q) * 64 + lane) * 8]);
          acc[gi] = __builtin_amdgcn_mfma_f32_16x16x32_bf16(a, b, acc[gi], 0, 0, 0);
        }
      }
      if (step > 0) {
        #pragma unroll
        for (int kc = 0; kc < 2; ++kc) {
          short8 a = *reinterpret_cast<const short8*>(&h2r[hr[kc]]);
          #pragma unroll
          for (int gi = 0; gi < 4; ++gi) {
            short8 b = *reinterpret_cast<const short8*>(&Wphh2[((kc * 16 + gi * 4 + q) * 64 + lane) * 8]);
            acc[gi] = __builtin_amdgcn_mfma_f32_16x16x32_bf16(a, b, acc[gi], 0, 0, 0);
          }
        }
      }
      #pragma unroll
      for (int jr = 0; jr < 4; ++jr) {
        float gi_ = acc[0][jr], gf = acc[1][jr], gg = acc[2][jr], go = acc[3][jr];
        float cc = sigf(gf) * c2[q * 4 + jr] + sigf(gi_) * tanhf_(gg);
        c2[q * 4 + jr] = cc;
        float h = sigf(go) * tanhf_(cc);
        int r = g * 4 + jr, j = q * 16 + c;
        h2w[(r * 64 + j) ^ ((r & 7) << 3)] = f2bf(h);
        if (step == TWIN - 1) out[(size_t)(tile * 16 + r) * OUTC + HD + j] = h;
      }
    }
  }
}

// skip connection S -> out cols 128..141
__global__ __launch_bounds__(256) void k_out_s(const float* __restrict__ x,
                                               float* __restrict__ out) {
  int idx = blockIdx.x * 256 + threadIdx.x;
  if (idx < NODES * 14) {
    int n = idx / 14, c = idx - n * 14;
    float v = (c < CIN) ? x[n * CIN + c]
                        : x[((c - (CIN - 1)) * NODES + n) * CIN + (CIN - 1)];
    out[(size_t)n * OUTC + 128 + c] = v;
  }
}

extern "C" void kernel_launch(void* const* d_in, const int* in_sizes, int n_in,
                              void* d_out, int out_size, void* d_ws, size_t ws_size,
                              hipStream_t stream) {
  const float* x      = (const float*)d_in[0];
  const int*   ei     = (const int*)d_in[1];
  const float* ew     = (const float*)d_in[2];
  const float* W1     = (const float*)d_in[3];
  const float* b1     = (const float*)d_in[4];
  const float* W2     = (const float*)d_in[5];
  const float* b2     = (const float*)d_in[6];
  const float* gamma1 = (const float*)d_in[7];
  const float* beta1  = (const float*)d_in[8];
  const float* gamma2 = (const float*)d_in[9];
  const float* beta2  = (const float*)d_in[10];
  const float* Wih1   = (const float*)d_in[11];
  const float* Whh1   = (const float*)d_in[12];
  const float* bih1   = (const float*)d_in[13];
  const float* bhh1   = (const float*)d_in[14];
  const float* Wih2   = (const float*)d_in[15];
  const float* Whh2   = (const float*)d_in[16];
  const float* bih2   = (const float*)d_in[17];
  const float* bhh2   = (const float*)d_in[18];
  const int* srcI = ei;
  const int* dstI = ei + NE;
  float* out = (float*)d_out;

  char* base = (char*)d_ws;
  size_t off = 0;
  auto alloc = [&](size_t bytes) -> void* {
    void* p = base + off;
    off = (off + bytes + 255) & ~(size_t)255;
    return p;
  };
  // small
  float* dinv   = (float*)alloc(N_TOT * 4);
  ushort* Wp1   = (ushort*)alloc(32768 * 2);   // [4kc][16nt][64][8] (BN-scaled)
  ushort* Wphh1 = (ushort*)alloc(16384 * 2);
  ushort* Wpih2 = (ushort*)alloc(16384 * 2);
  ushort* Wphh2 = (ushort*)alloc(16384 * 2);
  ushort* Wp2   = (ushort*)alloc(4096 * 2);    // W2 B-frags (BN-scaled)
  float* c2b    = (float*)alloc(HD * 4);
  float* biasL1 = (float*)alloc(256 * 4);
  float* bsum2  = (float*)alloc(256 * 4);
  float* scale1 = (float*)alloc(HD * 4);
  float* shift1 = (float*)alloc(HD * 4);
  float* scale2 = (float*)alloc(HD * 4);
  float* shift2 = (float*)alloc(HD * 4);
  // zeroed-every-call region (contiguous)
  char* zstart = base + off;
  int*   cursor = (int*)alloc(N_TOT * 4);
  float* sum1   = (float*)alloc(HD * 4);
  float* sq1    = (float*)alloc(HD * 4);
  float* sum2   = (float*)alloc(HD * 4);
  float* sq2    = (float*)alloc(HD * 4);
  size_t zbytes = (size_t)((base + off) - zstart);
  // big buffers (~125 MB)
  int2*   csr = (int2*)alloc((size_t)N_TOT * SLOTS * 8);   // 71.68 MB
  ushort* Hb  = (ushort*)alloc((size_t)N_TOT * HD * 2);
  ushort* A1  = (ushort*)alloc((size_t)N_TOT * HD * 2);
  ushort* A2  = (ushort*)alloc((size_t)N_TOT * HD * 2);

  hipMemsetAsync(zstart, 0, zbytes, stream);
  k_pack<<<(16384 + 255) / 256, 256, 0, stream>>>(Whh1, Wphh1, 64);
  k_pack<<<(16384 + 255) / 256, 256, 0, stream>>>(Wih2, Wpih2, 64);
  k_pack<<<(16384 + 255) / 256, 256, 0, stream>>>(Whh2, Wphh2, 64);
  k_bsum2<<<1, 256, 0, stream>>>(bih2, bhh2, bsum2);
  k_fill_direct<<<(NE + 255) / 256, 256, 0, stream>>>(srcI, dstI, ew, cursor, csr);
  k_degrow<<<1024, 256, 0, stream>>>(cursor, csr, dinv);
  k_gcn1<<<2048, 256, 0, stream>>>(x, dinv, cursor, csr, W1, b1, A1, sum1, sq1);
  k_bnfin<<<1, 64, 0, stream>>>(sum1, sq1, gamma1, beta1, scale1, shift1);
  k_pack_w2<<<(4096 + 255) / 256, 256, 0, stream>>>(W2, scale1, Wp2);
  k_hbias<<<1, 64, 0, stream>>>(W2, shift1, c2b);
  k_gemm_h2<<<(HTILES + 3) / 4, 256, 0, stream>>>(A1, Wp2, c2b, Hb);
  k_spmm2<<<2048, 256, 0, stream>>>(Hb, dinv, cursor, csr, b2, A2, sum2, sq2);
  k_bnfin<<<1, 64, 0, stream>>>(sum2, sq2, gamma2, beta2, scale2, shift2);
  k_pack_s<<<(32768 + 255) / 256, 256, 0, stream>>>(Wih1, scale1, scale2, Wp1);
  k_bias1<<<1, 256, 0, stream>>>(Wih1, bih1, bhh1, shift1, shift2, biasL1);
  k_lstm4<<<(NTILES + 3) / 4, 256, 0, stream>>>(A1, A2, Wp1, Wphh1, Wpih2, Wphh2,
                                                biasL1, bsum2, out);
  k_out_s<<<(NODES * 14 + 255) / 256, 256, 0, stream>>>(x, out);
}

// Round 7
// 824.123 us; speedup vs baseline: 1.9046x; 1.0347x over previous
//
#include <hip/hip_runtime.h>

// MPNNLSTM round 6:
//  - k_spmm2: 8-deep explicit gather pipeline on padded rows; gathers pre-scaled
//    Hbs = dinv*Hb (written by k_gemm_h2) -> 2 loads/edge, 8 in flight
//  - k_prep: dinv + row-pad-to-8 + xs = bf16(dinv*x) in one pass
//  - k_gcn1: gathers xs (16B/row, no dinv load), branchless padded loop
//  - k_lstm5: 4-wave cooperative tile (wave = gate-column group q), 2 barriers/step

#define N_TOT 140000
#define NE    2240000
#define NODES 20000
#define TWIN  7
#define CIN   8
#define HD    64
#define OUTC  142
#define SLOTS 64          // padded CSR row capacity (max deg ~36 for Poisson(16))
#define NTILES 1250       // 20000/16 node-tiles
#define HTILES 8750       // 140000/16 row-tiles for gemm_h

typedef __attribute__((ext_vector_type(8))) short short8;
typedef __attribute__((ext_vector_type(4))) float f32x4;

static __device__ __forceinline__ float fast_exp2(float x) {
  return __builtin_amdgcn_exp2f(x);
}
static __device__ __forceinline__ float fast_rcp(float x) {
  return __builtin_amdgcn_rcpf(x);
}
static __device__ __forceinline__ float sigf(float x) {
  return fast_rcp(1.0f + fast_exp2(-1.4426950408889634f * x));
}
static __device__ __forceinline__ float tanhf_(float x) {
  return 1.0f - 2.0f * fast_rcp(1.0f + fast_exp2(2.8853900817779268f * x));
}
static __device__ __forceinline__ ushort f2bf(float x) {
  union { float f; uint32_t u; } c; c.f = x;
  uint32_t r = c.u + 0x7fff + ((c.u >> 16) & 1);   // RNE
  return (ushort)(r >> 16);
}
static __device__ __forceinline__ float bf2f(ushort h) {
  union { uint32_t u; float f; } c; c.u = ((uint32_t)h) << 16; return c.f;
}

// Pack W [256][K] (row-major f32, gate-major) into MFMA B-fragment order.
__global__ __launch_bounds__(256) void k_pack(const float* __restrict__ W,
                                              ushort* __restrict__ Wp, int K) {
  int idx = blockIdx.x * 256 + threadIdx.x;
  int total = (K >> 5) * 16 * 64 * 8;
  if (idx < total) {
    int j = idx & 7, lane = (idx >> 3) & 63, nt = (idx >> 9) & 15, kc = idx >> 13;
    int g = nt * 16 + (lane & 15);
    int k = kc * 32 + ((lane >> 4) << 3) + j;
    Wp[idx] = f2bf(W[g * K + k]);
  }
}

// Pack Wih1 [256][128] with per-k BN scale folded in (k<64: scale1, else scale2).
__global__ __launch_bounds__(256) void k_pack_s(const float* __restrict__ W,
                                                const float* __restrict__ scale1,
                                                const float* __restrict__ scale2,
                                                ushort* __restrict__ Wp) {
  int idx = blockIdx.x * 256 + threadIdx.x;
  if (idx < 32768) {
    int j = idx & 7, lane = (idx >> 3) & 63, nt = (idx >> 9) & 15, kc = idx >> 13;
    int g = nt * 16 + (lane & 15);
    int k = kc * 32 + ((lane >> 4) << 3) + j;
    float s = (k < HD) ? scale1[k] : scale2[k - HD];
    Wp[idx] = f2bf(W[g * 128 + k] * s);
  }
}

// Pack W2 [64k][64j] with scale1[k] folded, B-frag order.
__global__ __launch_bounds__(256) void k_pack_w2(const float* __restrict__ W2,
                                                 const float* __restrict__ scale1,
                                                 ushort* __restrict__ Wp2) {
  int idx = blockIdx.x * 256 + threadIdx.x;
  if (idx < 4096) {
    int jj = idx & 7, lane = (idx >> 3) & 63, nt = (idx >> 9) & 3, kc = idx >> 11;
    int j = nt * 16 + (lane & 15);
    int k = kc * 32 + ((lane >> 4) << 3) + jj;
    Wp2[idx] = f2bf(scale1[k] * W2[k * 64 + j]);
  }
}

// c2b[j] = sum_k shift1[k] * W2[k][j]
__global__ __launch_bounds__(64) void k_hbias(const float* __restrict__ W2,
                                              const float* __restrict__ shift1,
                                              float* __restrict__ c2b) {
  int j = threadIdx.x;
  float s = 0.f;
  for (int k = 0; k < HD; ++k) s += shift1[k] * W2[k * 64 + j];
  c2b[j] = s;
}

// biasL1[col] = bih1+bhh1 + sum_k Wih1[col][k]*shift_k
__global__ __launch_bounds__(256) void k_bias1(const float* __restrict__ Wih1,
                                               const float* __restrict__ bih1,
                                               const float* __restrict__ bhh1,
                                               const float* __restrict__ shift1,
                                               const float* __restrict__ shift2,
                                               float* __restrict__ biasL1) {
  int col = threadIdx.x;
  float s = bih1[col] + bhh1[col];
  for (int k = 0; k < HD; ++k) s += Wih1[col * 128 + k] * shift1[k];
  for (int k = 0; k < HD; ++k) s += Wih1[col * 128 + HD + k] * shift2[k];
  biasL1[col] = s;
}

__global__ __launch_bounds__(256) void k_bsum2(const float* __restrict__ bih2,
                                               const float* __restrict__ bhh2,
                                               float* __restrict__ bsum2) {
  int t = threadIdx.x;
  bsum2[t] = bih2[t] + bhh2[t];
}

// Direct CSR placement: csr[dst*SLOTS + pos] = (src, raw w).
__global__ __launch_bounds__(256) void k_fill_direct(const int* __restrict__ srcI,
                                                     const int* __restrict__ dstI,
                                                     const float* __restrict__ w,
                                                     int* cursor,
                                                     int2* __restrict__ csr) {
  int e = blockIdx.x * 256 + threadIdx.x;
  if (e < NE) {
    int s = srcI[e], d = dstI[e];
    int pos = atomicAdd(&cursor[d], 1);
    if (pos < SLOTS) {
      int2 cv; cv.x = s; cv.y = __float_as_int(w[e]);
      csr[(size_t)d * SLOTS + pos] = cv;
    }
  }
}

// Per-row prep: dinv[d] = rsqrt(1+sum w); pad row to multiple of 8 with (0,0);
// xs[d][0..7] = bf16(dinv[d] * x[d][0..7]). Wave per row.
__global__ __launch_bounds__(256) void k_prep(const int* __restrict__ cursor,
                                              int2* __restrict__ csr,
                                              const float* __restrict__ x,
                                              float* __restrict__ dinv,
                                              ushort* __restrict__ xs) {
  int wv = (blockIdx.x * 256 + threadIdx.x) >> 6;
  int lane = threadIdx.x & 63;
  int nw = (gridDim.x * 256) >> 6;
  for (int d = wv; d < N_TOT; d += nw) {
    int len = min(cursor[d], SLOTS);
    float w = (lane < len) ? __int_as_float(csr[(size_t)d * SLOTS + lane].y) : 0.f;
    #pragma unroll
    for (int m = 1; m < 64; m <<= 1) w += __shfl_xor(w, m);
    float di = rsqrtf(1.0f + w);
    if (lane == 0) dinv[d] = di;
    int lenr = (len + 7) & ~7;
    if (lane >= len && lane < lenr) {
      int2 z; z.x = 0; z.y = 0;
      csr[(size_t)d * SLOTS + lane] = z;
    }
    if (lane < CIN) xs[d * CIN + lane] = f2bf(di * x[(size_t)d * CIN + lane]);
  }
}

// GCN layer 1 fused: gather xs (pre-scaled bf16) + GEMM(W1) + relu + BN stats.
__global__ __launch_bounds__(256) void k_gcn1(const ushort* __restrict__ xs,
                                              const float* __restrict__ dinv,
                                              const int* __restrict__ cursor,
                                              const int2* __restrict__ csr,
                                              const float* __restrict__ W1,
                                              const float* __restrict__ b1,
                                              ushort* __restrict__ A1,
                                              float* gsum, float* gsq) {
  __shared__ float w1s[CIN * HD];
  __shared__ float b1s[HD];
  for (int i = threadIdx.x; i < CIN * HD; i += 256) w1s[i] = W1[i];
  if (threadIdx.x < HD) b1s[threadIdx.x] = b1[threadIdx.x];
  __syncthreads();
  int wid = (blockIdx.x * 256 + threadIdx.x) >> 6;
  int lane = threadIdx.x & 63;
  int nw = (gridDim.x * 256) >> 6;
  int e8 = lane >> 3, c8 = lane & 7;
  float s = 0.f, q = 0.f;
  for (int d = wid; d < N_TOT; d += nw) {
    const int2* row = csr + ((size_t)d << 6);
    int len = min(cursor[d], SLOTS);
    int lenr = (len + 7) & ~7;
    float part = 0.f;
    #pragma unroll 4
    for (int i = e8; i < lenr; i += 8) {
      int2 cv = row[i];
      part += __int_as_float(cv.y) * bf2f(xs[(size_t)cv.x * CIN + c8]);
    }
    part += __shfl_xor(part, 8);
    part += __shfl_xor(part, 16);
    part += __shfl_xor(part, 32);
    part += bf2f(xs[(size_t)d * CIN + c8]);   // self term (xs includes dinv)
    float di = dinv[d];
    float acc = b1s[lane];
    #pragma unroll
    for (int c = 0; c < CIN; ++c) {
      float aggc = di * __shfl(part, c);
      acc += aggc * w1s[c * HD + lane];
    }
    float r = fmaxf(acc, 0.f);
    A1[(size_t)d * HD + lane] = f2bf(r);
    s += r; q += r * r;
  }
  atomicAdd(&gsum[lane], s);
  atomicAdd(&gsq[lane], q);
}

__global__ __launch_bounds__(64) void k_bnfin(const float* __restrict__ gsum,
                                              const float* __restrict__ gsq,
                                              const float* __restrict__ gamma,
                                              const float* __restrict__ beta,
                                              float* __restrict__ scale,
                                              float* __restrict__ shift) {
  int j = threadIdx.x;
  if (j < HD) {
    float m = gsum[j] / (float)N_TOT;
    float v = gsq[j] / (float)N_TOT - m * m;
    float sc = gamma[j] * rsqrtf(v + 1e-5f);
    scale[j] = sc;
    shift[j] = beta[j] - m * sc;
  }
}

// Hbs = bf16( dinv[row] * (BN1(A1) @ W2) ) via MFMA (pre-scaled for spmm2 gathers).
__global__ __launch_bounds__(256) void k_gemm_h2(const ushort* __restrict__ A1,
                                                 const ushort* __restrict__ Wp2,
                                                 const float* __restrict__ c2b,
                                                 const float* __restrict__ dinv,
                                                 ushort* __restrict__ Hbs) {
  int t = threadIdx.x, wid = t >> 6, lane = t & 63;
  int tile = blockIdx.x * 4 + wid;
  if (tile >= HTILES) return;
  int g = lane >> 4, c = lane & 15;
  const ushort* ap = A1 + ((size_t)(tile * 16 + c)) * HD + g * 8;
  f32x4 acc[4];
  #pragma unroll
  for (int nt = 0; nt < 4; ++nt) {
    float bv = c2b[nt * 16 + c];
    acc[nt] = (f32x4){bv, bv, bv, bv};
  }
  #pragma unroll
  for (int kc = 0; kc < 2; ++kc) {
    short8 a = *reinterpret_cast<const short8*>(ap + kc * 32);
    #pragma unroll
    for (int nt = 0; nt < 4; ++nt) {
      short8 b = *reinterpret_cast<const short8*>(&Wp2[((kc * 4 + nt) * 64 + lane) * 8]);
      acc[nt] = __builtin_amdgcn_mfma_f32_16x16x32_bf16(a, b, acc[nt], 0, 0, 0);
    }
  }
  float dv[4];
  #pragma unroll
  for (int jr = 0; jr < 4; ++jr) dv[jr] = dinv[tile * 16 + g * 4 + jr];
  #pragma unroll
  for (int nt = 0; nt < 4; ++nt)
    #pragma unroll
    for (int jr = 0; jr < 4; ++jr) {
      int r = g * 4 + jr;
      Hbs[((size_t)(tile * 16 + r)) * HD + nt * 16 + c] = f2bf(dv[jr] * acc[nt][jr]);
    }
}

// GCN layer 2 aggregation: wave per dst row, 8-deep gather pipeline on padded rows.
// pre = dinv[d] * ( sum w*Hbs[src] + Hbs[d] ); relu; bf16 out; BN stats.
__global__ __launch_bounds__(256) void k_spmm2(const ushort* __restrict__ Hbs,
                                               const float* __restrict__ dinv,
                                               const int* __restrict__ cursor,
                                               const int2* __restrict__ csr,
                                               const float* __restrict__ bias,
                                               ushort* __restrict__ A2,
                                               float* gsum, float* gsq) {
  int wid = (blockIdx.x * 256 + threadIdx.x) >> 6;
  int lane = threadIdx.x & 63;
  int nw = (gridDim.x * 256) >> 6;
  float b = bias[lane];
  float s = 0.f, q = 0.f;
  for (int d = wid; d < N_TOT; d += nw) {
    const int2* row = csr + ((size_t)d << 6);
    int len = min(cursor[d], SLOTS);
    int lenr = (len + 7) & ~7;
    float acc = bf2f(Hbs[(((size_t)d) << 6) + lane]);   // self term
    for (int i0 = 0; i0 < lenr; i0 += 8) {
      int2 cv[8];
      #pragma unroll
      for (int j = 0; j < 8; ++j) cv[j] = row[i0 + j];
      ushort hv[8];
      #pragma unroll
      for (int j = 0; j < 8; ++j)
        hv[j] = Hbs[(((size_t)cv[j].x) << 6) + lane];
      #pragma unroll
      for (int j = 0; j < 8; ++j)
        acc = fmaf(__int_as_float(cv[j].y), bf2f(hv[j]), acc);
    }
    float r = fmaxf(dinv[d] * acc + b, 0.f);
    A2[(((size_t)d) << 6) + lane] = f2bf(r);
    s += r; q += r * r;
  }
  atomicAdd(&gsum[lane], s);
  atomicAdd(&gsq[lane], q);
}

// ---------------------------------------------------------------------------
// Cooperative fused 2-layer LSTM: block = 4 waves = 1 tile (16 nodes).
// Wave q owns gate-column group q (nt = gi*4+q); h1/h2 shared in LDS
// (XOR-swizzled, parity double-buffered); 2 __syncthreads per step.
// ---------------------------------------------------------------------------
__global__ __launch_bounds__(256) void k_lstm5(const ushort* __restrict__ A1,
                                               const ushort* __restrict__ A2,
                                               const ushort* __restrict__ Wp1,
                                               const ushort* __restrict__ Wphh1,
                                               const ushort* __restrict__ Wpih2,
                                               const ushort* __restrict__ Wphh2,
                                               const float* __restrict__ biasL1,
                                               const float* __restrict__ bsum2,
                                               float* __restrict__ out) {
  __shared__ ushort h1s[2][1024];   // [parity][16x64 swizzled]
  __shared__ ushort h2s[2][1024];
  int t = threadIdx.x;
  int q = t >> 6, lane = t & 63;
  int tile = blockIdx.x;
  int g = lane >> 4, c = lane & 15;

  float c1[4], c2[4];
  #pragma unroll
  for (int i = 0; i < 4; ++i) { c1[i] = 0.f; c2[i] = 0.f; }

  int hr[2];
  #pragma unroll
  for (int kc = 0; kc < 2; ++kc)
    hr[kc] = (c * 64 + kc * 32 + g * 8) ^ ((c & 7) << 3);
  int hw[4];
  #pragma unroll
  for (int jr = 0; jr < 4; ++jr) {
    int r = g * 4 + jr, j = q * 16 + c;
    hw[jr] = (r * 64 + j) ^ ((r & 7) << 3);
  }
  float bL1[4], bL2[4];
  #pragma unroll
  for (int gi = 0; gi < 4; ++gi) {
    bL1[gi] = biasL1[gi * 64 + q * 16 + c];
    bL2[gi] = bsum2[gi * 64 + q * 16 + c];
  }

  for (int step = 0; step < TWIN; ++step) {
    int pw = step & 1, pr = pw ^ 1;
    size_t nodeoff = (size_t)(step * NODES + tile * 16 + c) * HD + g * 8;
    const ushort* a1p = A1 + nodeoff;
    const ushort* a2p = A2 + nodeoff;

    // ===== layer 1: gates(q) = Xc @ Wih1' + h1 @ Whh1' + b =====
    f32x4 acc[4];
    #pragma unroll
    for (int gi = 0; gi < 4; ++gi) acc[gi] = (f32x4){bL1[gi], bL1[gi], bL1[gi], bL1[gi]};
    #pragma unroll
    for (int kc = 0; kc < 4; ++kc) {
      const ushort* ap = (kc < 2) ? (a1p + kc * 32) : (a2p + (kc - 2) * 32);
      short8 a = *reinterpret_cast<const short8*>(ap);
      #pragma unroll
      for (int gi = 0; gi < 4; ++gi) {
        short8 b = *reinterpret_cast<const short8*>(&Wp1[((kc * 16 + gi * 4 + q) * 64 + lane) * 8]);
        acc[gi] = __builtin_amdgcn_mfma_f32_16x16x32_bf16(a, b, acc[gi], 0, 0, 0);
      }
    }
    if (step > 0) {
      #pragma unroll
      for (int kc = 0; kc < 2; ++kc) {
        short8 a = *reinterpret_cast<const short8*>(&h1s[pr][hr[kc]]);
        #pragma unroll
        for (int gi = 0; gi < 4; ++gi) {
          short8 b = *reinterpret_cast<const short8*>(&Wphh1[((kc * 16 + gi * 4 + q) * 64 + lane) * 8]);
          acc[gi] = __builtin_amdgcn_mfma_f32_16x16x32_bf16(a, b, acc[gi], 0, 0, 0);
        }
      }
    }
    #pragma unroll
    for (int jr = 0; jr < 4; ++jr) {
      float gi_ = acc[0][jr], gf = acc[1][jr], gg = acc[2][jr], go = acc[3][jr];
      float cc = sigf(gf) * c1[jr] + sigf(gi_) * tanhf_(gg);
      c1[jr] = cc;
      float h = sigf(go) * tanhf_(cc);
      h1s[pw][hw[jr]] = f2bf(h);
      if (step == TWIN - 1) {
        int r = g * 4 + jr, j = q * 16 + c;
        out[(size_t)(tile * 16 + r) * OUTC + j] = h;
      }
    }
    __syncthreads();

    // ===== layer 2: gates(q) = h1 @ Wih2' + h2 @ Whh2' + b =====
    #pragma unroll
    for (int gi = 0; gi < 4; ++gi) acc[gi] = (f32x4){bL2[gi], bL2[gi], bL2[gi], bL2[gi]};
    #pragma unroll
    for (int kc = 0; kc < 2; ++kc) {
      short8 a = *reinterpret_cast<const short8*>(&h1s[pw][hr[kc]]);
      #pragma unroll
      for (int gi = 0; gi < 4; ++gi) {
        short8 b = *reinterpret_cast<const short8*>(&Wpih2[((kc * 16 + gi * 4 + q) * 64 + lane) * 8]);
        acc[gi] = __builtin_amdgcn_mfma_f32_16x16x32_bf16(a, b, acc[gi], 0, 0, 0);
      }
    }
    if (step > 0) {
      #pragma unroll
      for (int kc = 0; kc < 2; ++kc) {
        short8 a = *reinterpret_cast<const short8*>(&h2s[pr][hr[kc]]);
        #pragma unroll
        for (int gi = 0; gi < 4; ++gi) {
          short8 b = *reinterpret_cast<const short8*>(&Wphh2[((kc * 16 + gi * 4 + q) * 64 + lane) * 8]);
          acc[gi] = __builtin_amdgcn_mfma_f32_16x16x32_bf16(a, b, acc[gi], 0, 0, 0);
        }
      }
    }
    #pragma unroll
    for (int jr = 0; jr < 4; ++jr) {
      float gi_ = acc[0][jr], gf = acc[1][jr], gg = acc[2][jr], go = acc[3][jr];
      float cc = sigf(gf) * c2[jr] + sigf(gi_) * tanhf_(gg);
      c2[jr] = cc;
      float h = sigf(go) * tanhf_(cc);
      h2s[pw][hw[jr]] = f2bf(h);
      if (step == TWIN - 1) {
        int r = g * 4 + jr, j = q * 16 + c;
        out[(size_t)(tile * 16 + r) * OUTC + HD + j] = h;
      }
    }
    __syncthreads();
  }
}

// skip connection S -> out cols 128..141
__global__ __launch_bounds__(256) void k_out_s(const float* __restrict__ x,
                                               float* __restrict__ out) {
  int idx = blockIdx.x * 256 + threadIdx.x;
  if (idx < NODES * 14) {
    int n = idx / 14, c = idx - n * 14;
    float v = (c < CIN) ? x[n * CIN + c]
                        : x[((c - (CIN - 1)) * NODES + n) * CIN + (CIN - 1)];
    out[(size_t)n * OUTC + 128 + c] = v;
  }
}

extern "C" void kernel_launch(void* const* d_in, const int* in_sizes, int n_in,
                              void* d_out, int out_size, void* d_ws, size_t ws_size,
                              hipStream_t stream) {
  const float* x      = (const float*)d_in[0];
  const int*   ei     = (const int*)d_in[1];
  const float* ew     = (const float*)d_in[2];
  const float* W1     = (const float*)d_in[3];
  const float* b1     = (const float*)d_in[4];
  const float* W2     = (const float*)d_in[5];
  const float* b2     = (const float*)d_in[6];
  const float* gamma1 = (const float*)d_in[7];
  const float* beta1  = (const float*)d_in[8];
  const float* gamma2 = (const float*)d_in[9];
  const float* beta2  = (const float*)d_in[10];
  const float* Wih1   = (const float*)d_in[11];
  const float* Whh1   = (const float*)d_in[12];
  const float* bih1   = (const float*)d_in[13];
  const float* bhh1   = (const float*)d_in[14];
  const float* Wih2   = (const float*)d_in[15];
  const float* Whh2   = (const float*)d_in[16];
  const float* bih2   = (const float*)d_in[17];
  const float* bhh2   = (const float*)d_in[18];
  const int* srcI = ei;
  const int* dstI = ei + NE;
  float* out = (float*)d_out;

  char* base = (char*)d_ws;
  size_t off = 0;
  auto alloc = [&](size_t bytes) -> void* {
    void* p = base + off;
    off = (off + bytes + 255) & ~(size_t)255;
    return p;
  };
  // small
  float* dinv   = (float*)alloc(N_TOT * 4);
  ushort* xs    = (ushort*)alloc((size_t)N_TOT * CIN * 2);   // dinv*x, bf16
  ushort* Wp1   = (ushort*)alloc(32768 * 2);   // [4kc][16nt][64][8] (BN-scaled)
  ushort* Wphh1 = (ushort*)alloc(16384 * 2);
  ushort* Wpih2 = (ushort*)alloc(16384 * 2);
  ushort* Wphh2 = (ushort*)alloc(16384 * 2);
  ushort* Wp2   = (ushort*)alloc(4096 * 2);    // W2 B-frags (BN-scaled)
  float* c2b    = (float*)alloc(HD * 4);
  float* biasL1 = (float*)alloc(256 * 4);
  float* bsum2  = (float*)alloc(256 * 4);
  float* scale1 = (float*)alloc(HD * 4);
  float* shift1 = (float*)alloc(HD * 4);
  float* scale2 = (float*)alloc(HD * 4);
  float* shift2 = (float*)alloc(HD * 4);
  // zeroed-every-call region (contiguous)
  char* zstart = base + off;
  int*   cursor = (int*)alloc(N_TOT * 4);
  float* sum1   = (float*)alloc(HD * 4);
  float* sq1    = (float*)alloc(HD * 4);
  float* sum2   = (float*)alloc(HD * 4);
  float* sq2    = (float*)alloc(HD * 4);
  size_t zbytes = (size_t)((base + off) - zstart);
  // big buffers (~125 MB)
  int2*   csr = (int2*)alloc((size_t)N_TOT * SLOTS * 8);   // 71.68 MB
  ushort* Hbs = (ushort*)alloc((size_t)N_TOT * HD * 2);
  ushort* A1  = (ushort*)alloc((size_t)N_TOT * HD * 2);
  ushort* A2  = (ushort*)alloc((size_t)N_TOT * HD * 2);

  hipMemsetAsync(zstart, 0, zbytes, stream);
  k_pack<<<(16384 + 255) / 256, 256, 0, stream>>>(Whh1, Wphh1, 64);
  k_pack<<<(16384 + 255) / 256, 256, 0, stream>>>(Wih2, Wpih2, 64);
  k_pack<<<(16384 + 255) / 256, 256, 0, stream>>>(Whh2, Wphh2, 64);
  k_bsum2<<<1, 256, 0, stream>>>(bih2, bhh2, bsum2);
  k_fill_direct<<<(NE + 255) / 256, 256, 0, stream>>>(srcI, dstI, ew, cursor, csr);
  k_prep<<<1024, 256, 0, stream>>>(cursor, csr, x, dinv, xs);
  k_gcn1<<<2048, 256, 0, stream>>>(xs, dinv, cursor, csr, W1, b1, A1, sum1, sq1);
  k_bnfin<<<1, 64, 0, stream>>>(sum1, sq1, gamma1, beta1, scale1, shift1);
  k_pack_w2<<<(4096 + 255) / 256, 256, 0, stream>>>(W2, scale1, Wp2);
  k_hbias<<<1, 64, 0, stream>>>(W2, shift1, c2b);
  k_gemm_h2<<<(HTILES + 3) / 4, 256, 0, stream>>>(A1, Wp2, c2b, dinv, Hbs);
  k_spmm2<<<2048, 256, 0, stream>>>(Hbs, dinv, cursor, csr, b2, A2, sum2, sq2);
  k_bnfin<<<1, 64, 0, stream>>>(sum2, sq2, gamma2, beta2, scale2, shift2);
  k_pack_s<<<(32768 + 255) / 256, 256, 0, stream>>>(Wih1, scale1, scale2, Wp1);
  k_bias1<<<1, 256, 0, stream>>>(Wih1, bih1, bhh1, shift1, shift2, biasL1);
  k_lstm5<<<NTILES, 256, 0, stream>>>(A1, A2, Wp1, Wphh1, Wpih2, Wphh2,
                                      biasL1, bsum2, out);
  k_out_s<<<(NODES * 14 + 255) / 256, 256, 0, stream>>>(x, out);
}

// Round 8
// 625.328 us; speedup vs baseline: 2.5101x; 1.3179x over previous
//
#include <hip/hip_runtime.h>

// MPNNLSTM round 7:
//  - pair-row interleaved gathers in k_gcn1/k_spmm2 (2 independent chains/wave)
//  - k_prep2 zero-pads both rows of a pair to the pair max -> branchless loops
//  - merged small kernels (16 -> 12 launches); k_out_s folded into k_lstm5

#define N_TOT 140000
#define NPAIR 70000
#define NE    2240000
#define NODES 20000
#define TWIN  7
#define CIN   8
#define HD    64
#define OUTC  142
#define SLOTS 64          // padded CSR row capacity (max deg ~36 for Poisson(16))
#define NTILES 1250       // 20000/16 node-tiles
#define HTILES 8750       // 140000/16 row-tiles for gemm_h

typedef __attribute__((ext_vector_type(8))) short short8;
typedef __attribute__((ext_vector_type(4))) float f32x4;

static __device__ __forceinline__ float fast_exp2(float x) {
  return __builtin_amdgcn_exp2f(x);
}
static __device__ __forceinline__ float fast_rcp(float x) {
  return __builtin_amdgcn_rcpf(x);
}
static __device__ __forceinline__ float sigf(float x) {
  return fast_rcp(1.0f + fast_exp2(-1.4426950408889634f * x));
}
static __device__ __forceinline__ float tanhf_(float x) {
  return 1.0f - 2.0f * fast_rcp(1.0f + fast_exp2(2.8853900817779268f * x));
}
static __device__ __forceinline__ ushort f2bf(float x) {
  union { float f; uint32_t u; } c; c.f = x;
  uint32_t r = c.u + 0x7fff + ((c.u >> 16) & 1);   // RNE
  return (ushort)(r >> 16);
}
static __device__ __forceinline__ float bf2f(ushort h) {
  union { uint32_t u; float f; } c; c.u = ((uint32_t)h) << 16; return c.f;
}

// blocks 0..191: pack {Whh1, Wih2, Whh2} (K=64) into B-frag order; block 192: bsum2.
__global__ __launch_bounds__(256) void k_wpack0(const float* __restrict__ Whh1,
                                                const float* __restrict__ Wih2,
                                                const float* __restrict__ Whh2,
                                                const float* __restrict__ bih2,
                                                const float* __restrict__ bhh2,
                                                ushort* __restrict__ Wphh1,
                                                ushort* __restrict__ Wpih2,
                                                ushort* __restrict__ Wphh2,
                                                float* __restrict__ bsum2) {
  int b = blockIdx.x;
  if (b < 192) {
    int which = b >> 6;
    int idx = (b & 63) * 256 + threadIdx.x;
    const float* W = (which == 0) ? Whh1 : (which == 1) ? Wih2 : Whh2;
    ushort* Wp = (which == 0) ? Wphh1 : (which == 1) ? Wpih2 : Wphh2;
    int j = idx & 7, lane = (idx >> 3) & 63, nt = (idx >> 9) & 15, kc = idx >> 13;
    int g = nt * 16 + (lane & 15);
    int k = kc * 32 + ((lane >> 4) << 3) + j;
    Wp[idx] = f2bf(W[g * 64 + k]);
  } else {
    bsum2[threadIdx.x] = bih2[threadIdx.x] + bhh2[threadIdx.x];
  }
}

// blocks 0..15: pack W2 with scale1 folded; block 16: c2b = shift1^T W2.
__global__ __launch_bounds__(256) void k_mid1(const float* __restrict__ W2,
                                              const float* __restrict__ scale1,
                                              const float* __restrict__ shift1,
                                              ushort* __restrict__ Wp2,
                                              float* __restrict__ c2b) {
  int b = blockIdx.x;
  if (b < 16) {
    int idx = b * 256 + threadIdx.x;
    int jj = idx & 7, lane = (idx >> 3) & 63, nt = (idx >> 9) & 3, kc = idx >> 11;
    int j = nt * 16 + (lane & 15);
    int k = kc * 32 + ((lane >> 4) << 3) + jj;
    Wp2[idx] = f2bf(scale1[k] * W2[k * 64 + j]);
  } else if (threadIdx.x < HD) {
    int j = threadIdx.x;
    float s = 0.f;
    for (int k = 0; k < HD; ++k) s += shift1[k] * W2[k * 64 + j];
    c2b[j] = s;
  }
}

// blocks 0..127: pack Wih1 with scale folded; block 128: biasL1.
__global__ __launch_bounds__(256) void k_mid2(const float* __restrict__ Wih1,
                                              const float* __restrict__ scale1,
                                              const float* __restrict__ scale2,
                                              const float* __restrict__ shift1,
                                              const float* __restrict__ shift2,
                                              const float* __restrict__ bih1,
                                              const float* __restrict__ bhh1,
                                              ushort* __restrict__ Wp1,
                                              float* __restrict__ biasL1) {
  int b = blockIdx.x;
  if (b < 128) {
    int idx = b * 256 + threadIdx.x;
    int j = idx & 7, lane = (idx >> 3) & 63, nt = (idx >> 9) & 15, kc = idx >> 13;
    int g = nt * 16 + (lane & 15);
    int k = kc * 32 + ((lane >> 4) << 3) + j;
    float s = (k < HD) ? scale1[k] : scale2[k - HD];
    Wp1[idx] = f2bf(Wih1[g * 128 + k] * s);
  } else {
    int col = threadIdx.x;
    float s = bih1[col] + bhh1[col];
    for (int k = 0; k < HD; ++k) s += Wih1[col * 128 + k] * shift1[k];
    for (int k = 0; k < HD; ++k) s += Wih1[col * 128 + HD + k] * shift2[k];
    biasL1[col] = s;
  }
}

// Direct CSR placement: csr[dst*SLOTS + pos] = (src, raw w).
__global__ __launch_bounds__(256) void k_fill_direct(const int* __restrict__ srcI,
                                                     const int* __restrict__ dstI,
                                                     const float* __restrict__ w,
                                                     int* cursor,
                                                     int2* __restrict__ csr) {
  int e = blockIdx.x * 256 + threadIdx.x;
  if (e < NE) {
    int s = srcI[e], d = dstI[e];
    int pos = atomicAdd(&cursor[d], 1);
    if (pos < SLOTS) {
      int2 cv; cv.x = s; cv.y = __float_as_int(w[e]);
      csr[(size_t)d * SLOTS + pos] = cv;
    }
  }
}

// Pair prep: for rows (2p, 2p+1): dinv, zero-pad BOTH rows to pair-max (mult of 8),
// xs = bf16(dinv*x). Wave per pair.
__global__ __launch_bounds__(256) void k_prep2(const int* __restrict__ cursor,
                                               int2* __restrict__ csr,
                                               const float* __restrict__ x,
                                               float* __restrict__ dinv,
                                               ushort* __restrict__ xs) {
  int wv = (blockIdx.x * 256 + threadIdx.x) >> 6;
  int lane = threadIdx.x & 63;
  int nw = (gridDim.x * 256) >> 6;
  for (int p = wv; p < NPAIR; p += nw) {
    int dA = p * 2, dB = dA + 1;
    int lenA = min(cursor[dA], SLOTS), lenB = min(cursor[dB], SLOTS);
    int lenM = (max(lenA, lenB) + 7) & ~7;
    float wA = (lane < lenA) ? __int_as_float(csr[((size_t)dA << 6) + lane].y) : 0.f;
    float wB = (lane < lenB) ? __int_as_float(csr[((size_t)dB << 6) + lane].y) : 0.f;
    #pragma unroll
    for (int m = 1; m < 64; m <<= 1) {
      wA += __shfl_xor(wA, m);
      wB += __shfl_xor(wB, m);
    }
    float diA = rsqrtf(1.0f + wA);
    float diB = rsqrtf(1.0f + wB);
    if (lane == 0) { dinv[dA] = diA; dinv[dB] = diB; }
    int2 z; z.x = 0; z.y = 0;
    if (lane >= lenA && lane < lenM) csr[((size_t)dA << 6) + lane] = z;
    if (lane >= lenB && lane < lenM) csr[((size_t)dB << 6) + lane] = z;
    if (lane < CIN) xs[(size_t)dA * CIN + lane] = f2bf(diA * x[(size_t)dA * CIN + lane]);
    else if (lane < 2 * CIN) {
      int c = lane - CIN;
      xs[(size_t)dB * CIN + c] = f2bf(diB * x[(size_t)dB * CIN + c]);
    }
  }
}

// GCN layer 1, pair-interleaved: gather xs for rows dA,dB together; GEMM(W1)+relu+stats.
__global__ __launch_bounds__(256) void k_gcn1(const ushort* __restrict__ xs,
                                              const float* __restrict__ dinv,
                                              const int* __restrict__ cursor,
                                              const int2* __restrict__ csr,
                                              const float* __restrict__ W1,
                                              const float* __restrict__ b1,
                                              ushort* __restrict__ A1,
                                              float* gsum, float* gsq) {
  __shared__ float w1s[CIN * HD];
  __shared__ float b1s[HD];
  for (int i = threadIdx.x; i < CIN * HD; i += 256) w1s[i] = W1[i];
  if (threadIdx.x < HD) b1s[threadIdx.x] = b1[threadIdx.x];
  __syncthreads();
  int wv = (blockIdx.x * 256 + threadIdx.x) >> 6;
  int lane = threadIdx.x & 63;
  int nw = (gridDim.x * 256) >> 6;
  int e8 = lane >> 3, c8 = lane & 7;
  float s = 0.f, q = 0.f;
  for (int p = wv; p < NPAIR; p += nw) {
    int dA = p * 2, dB = dA + 1;
    const int2* rowA = csr + ((size_t)dA << 6);
    const int2* rowB = csr + ((size_t)dB << 6);
    int lenA = min(cursor[dA], SLOTS), lenB = min(cursor[dB], SLOTS);
    int lenM = (max(lenA, lenB) + 7) & ~7;
    float pA = 0.f, pB = 0.f;
    #pragma unroll 2
    for (int i = e8; i < lenM; i += 8) {
      int2 ca = rowA[i];
      int2 cb = rowB[i];
      pA += __int_as_float(ca.y) * bf2f(xs[(size_t)ca.x * CIN + c8]);
      pB += __int_as_float(cb.y) * bf2f(xs[(size_t)cb.x * CIN + c8]);
    }
    pA += __shfl_xor(pA, 8);  pB += __shfl_xor(pB, 8);
    pA += __shfl_xor(pA, 16); pB += __shfl_xor(pB, 16);
    pA += __shfl_xor(pA, 32); pB += __shfl_xor(pB, 32);
    pA += bf2f(xs[(size_t)dA * CIN + c8]);   // self term (xs includes dinv)
    pB += bf2f(xs[(size_t)dB * CIN + c8]);
    float diA = dinv[dA], diB = dinv[dB];
    float accA = b1s[lane], accB = b1s[lane];
    #pragma unroll
    for (int c = 0; c < CIN; ++c) {
      float w = w1s[c * HD + lane];
      accA += diA * __shfl(pA, c) * w;
      accB += diB * __shfl(pB, c) * w;
    }
    float rA = fmaxf(accA, 0.f), rB = fmaxf(accB, 0.f);
    A1[(size_t)dA * HD + lane] = f2bf(rA);
    A1[(size_t)dB * HD + lane] = f2bf(rB);
    s += rA + rB; q += rA * rA + rB * rB;
  }
  atomicAdd(&gsum[lane], s);
  atomicAdd(&gsq[lane], q);
}

__global__ __launch_bounds__(64) void k_bnfin(const float* __restrict__ gsum,
                                              const float* __restrict__ gsq,
                                              const float* __restrict__ gamma,
                                              const float* __restrict__ beta,
                                              float* __restrict__ scale,
                                              float* __restrict__ shift) {
  int j = threadIdx.x;
  if (j < HD) {
    float m = gsum[j] / (float)N_TOT;
    float v = gsq[j] / (float)N_TOT - m * m;
    float sc = gamma[j] * rsqrtf(v + 1e-5f);
    scale[j] = sc;
    shift[j] = beta[j] - m * sc;
  }
}

// Hbs = bf16( dinv[row] * (BN1(A1) @ W2) ) via MFMA (pre-scaled for spmm2 gathers).
__global__ __launch_bounds__(256) void k_gemm_h2(const ushort* __restrict__ A1,
                                                 const ushort* __restrict__ Wp2,
                                                 const float* __restrict__ c2b,
                                                 const float* __restrict__ dinv,
                                                 ushort* __restrict__ Hbs) {
  int t = threadIdx.x, wid = t >> 6, lane = t & 63;
  int tile = blockIdx.x * 4 + wid;
  if (tile >= HTILES) return;
  int g = lane >> 4, c = lane & 15;
  const ushort* ap = A1 + ((size_t)(tile * 16 + c)) * HD + g * 8;
  f32x4 acc[4];
  #pragma unroll
  for (int nt = 0; nt < 4; ++nt) {
    float bv = c2b[nt * 16 + c];
    acc[nt] = (f32x4){bv, bv, bv, bv};
  }
  #pragma unroll
  for (int kc = 0; kc < 2; ++kc) {
    short8 a = *reinterpret_cast<const short8*>(ap + kc * 32);
    #pragma unroll
    for (int nt = 0; nt < 4; ++nt) {
      short8 b = *reinterpret_cast<const short8*>(&Wp2[((kc * 4 + nt) * 64 + lane) * 8]);
      acc[nt] = __builtin_amdgcn_mfma_f32_16x16x32_bf16(a, b, acc[nt], 0, 0, 0);
    }
  }
  float dv[4];
  #pragma unroll
  for (int jr = 0; jr < 4; ++jr) dv[jr] = dinv[tile * 16 + g * 4 + jr];
  #pragma unroll
  for (int nt = 0; nt < 4; ++nt)
    #pragma unroll
    for (int jr = 0; jr < 4; ++jr) {
      int r = g * 4 + jr;
      Hbs[((size_t)(tile * 16 + r)) * HD + nt * 16 + c] = f2bf(dv[jr] * acc[nt][jr]);
    }
}

// GCN layer 2 aggregation, pair-interleaved: rows dA,dB per wave, 4-deep batches
// per row (8 gathers in flight). pre = dinv[d]*(sum w*Hbs[src] + Hbs[d]); relu.
__global__ __launch_bounds__(256) void k_spmm2(const ushort* __restrict__ Hbs,
                                               const float* __restrict__ dinv,
                                               const int* __restrict__ cursor,
                                               const int2* __restrict__ csr,
                                               const float* __restrict__ bias,
                                               ushort* __restrict__ A2,
                                               float* gsum, float* gsq) {
  int wv = (blockIdx.x * 256 + threadIdx.x) >> 6;
  int lane = threadIdx.x & 63;
  int nw = (gridDim.x * 256) >> 6;
  float b = bias[lane];
  float s = 0.f, q = 0.f;
  for (int p = wv; p < NPAIR; p += nw) {
    int dA = p * 2, dB = dA + 1;
    const int2* rowA = csr + ((size_t)dA << 6);
    const int2* rowB = csr + ((size_t)dB << 6);
    int lenA = min(cursor[dA], SLOTS), lenB = min(cursor[dB], SLOTS);
    int lenM = (max(lenA, lenB) + 7) & ~7;
    float accA = bf2f(Hbs[(((size_t)dA) << 6) + lane]);   // self terms
    float accB = bf2f(Hbs[(((size_t)dB) << 6) + lane]);
    for (int i0 = 0; i0 < lenM; i0 += 4) {
      int2 cvA[4], cvB[4];
      #pragma unroll
      for (int j = 0; j < 4; ++j) { cvA[j] = rowA[i0 + j]; cvB[j] = rowB[i0 + j]; }
      ushort hA[4], hB[4];
      #pragma unroll
      for (int j = 0; j < 4; ++j) {
        hA[j] = Hbs[(((size_t)cvA[j].x) << 6) + lane];
        hB[j] = Hbs[(((size_t)cvB[j].x) << 6) + lane];
      }
      #pragma unroll
      for (int j = 0; j < 4; ++j) {
        accA = fmaf(__int_as_float(cvA[j].y), bf2f(hA[j]), accA);
        accB = fmaf(__int_as_float(cvB[j].y), bf2f(hB[j]), accB);
      }
    }
    float rA = fmaxf(dinv[dA] * accA + b, 0.f);
    float rB = fmaxf(dinv[dB] * accB + b, 0.f);
    A2[(((size_t)dA) << 6) + lane] = f2bf(rA);
    A2[(((size_t)dB) << 6) + lane] = f2bf(rB);
    s += rA + rB; q += rA * rA + rB * rB;
  }
  atomicAdd(&gsum[lane], s);
  atomicAdd(&gsq[lane], q);
}

// ---------------------------------------------------------------------------
// Cooperative fused 2-layer LSTM (unchanged) + folded skip-connection write.
// ---------------------------------------------------------------------------
__global__ __launch_bounds__(256) void k_lstm5(const ushort* __restrict__ A1,
                                               const ushort* __restrict__ A2,
                                               const ushort* __restrict__ Wp1,
                                               const ushort* __restrict__ Wphh1,
                                               const ushort* __restrict__ Wpih2,
                                               const ushort* __restrict__ Wphh2,
                                               const float* __restrict__ biasL1,
                                               const float* __restrict__ bsum2,
                                               const float* __restrict__ x,
                                               float* __restrict__ out) {
  __shared__ ushort h1s[2][1024];   // [parity][16x64 swizzled]
  __shared__ ushort h2s[2][1024];
  int t = threadIdx.x;
  int q = t >> 6, lane = t & 63;
  int tile = blockIdx.x;
  int g = lane >> 4, c = lane & 15;

  float c1[4], c2[4];
  #pragma unroll
  for (int i = 0; i < 4; ++i) { c1[i] = 0.f; c2[i] = 0.f; }

  int hr[2];
  #pragma unroll
  for (int kc = 0; kc < 2; ++kc)
    hr[kc] = (c * 64 + kc * 32 + g * 8) ^ ((c & 7) << 3);
  int hw[4];
  #pragma unroll
  for (int jr = 0; jr < 4; ++jr) {
    int r = g * 4 + jr, j = q * 16 + c;
    hw[jr] = (r * 64 + j) ^ ((r & 7) << 3);
  }
  float bL1[4], bL2[4];
  #pragma unroll
  for (int gi = 0; gi < 4; ++gi) {
    bL1[gi] = biasL1[gi * 64 + q * 16 + c];
    bL2[gi] = bsum2[gi * 64 + q * 16 + c];
  }

  for (int step = 0; step < TWIN; ++step) {
    int pw = step & 1, pr = pw ^ 1;
    size_t nodeoff = (size_t)(step * NODES + tile * 16 + c) * HD + g * 8;
    const ushort* a1p = A1 + nodeoff;
    const ushort* a2p = A2 + nodeoff;

    // ===== layer 1: gates(q) = Xc @ Wih1' + h1 @ Whh1' + b =====
    f32x4 acc[4];
    #pragma unroll
    for (int gi = 0; gi < 4; ++gi) acc[gi] = (f32x4){bL1[gi], bL1[gi], bL1[gi], bL1[gi]};
    #pragma unroll
    for (int kc = 0; kc < 4; ++kc) {
      const ushort* ap = (kc < 2) ? (a1p + kc * 32) : (a2p + (kc - 2) * 32);
      short8 a = *reinterpret_cast<const short8*>(ap);
      #pragma unroll
      for (int gi = 0; gi < 4; ++gi) {
        short8 b = *reinterpret_cast<const short8*>(&Wp1[((kc * 16 + gi * 4 + q) * 64 + lane) * 8]);
        acc[gi] = __builtin_amdgcn_mfma_f32_16x16x32_bf16(a, b, acc[gi], 0, 0, 0);
      }
    }
    if (step > 0) {
      #pragma unroll
      for (int kc = 0; kc < 2; ++kc) {
        short8 a = *reinterpret_cast<const short8*>(&h1s[pr][hr[kc]]);
        #pragma unroll
        for (int gi = 0; gi < 4; ++gi) {
          short8 b = *reinterpret_cast<const short8*>(&Wphh1[((kc * 16 + gi * 4 + q) * 64 + lane) * 8]);
          acc[gi] = __builtin_amdgcn_mfma_f32_16x16x32_bf16(a, b, acc[gi], 0, 0, 0);
        }
      }
    }
    #pragma unroll
    for (int jr = 0; jr < 4; ++jr) {
      float gi_ = acc[0][jr], gf = acc[1][jr], gg = acc[2][jr], go = acc[3][jr];
      float cc = sigf(gf) * c1[jr] + sigf(gi_) * tanhf_(gg);
      c1[jr] = cc;
      float h = sigf(go) * tanhf_(cc);
      h1s[pw][hw[jr]] = f2bf(h);
      if (step == TWIN - 1) {
        int r = g * 4 + jr, j = q * 16 + c;
        out[(size_t)(tile * 16 + r) * OUTC + j] = h;
      }
    }
    __syncthreads();

    // ===== layer 2: gates(q) = h1 @ Wih2' + h2 @ Whh2' + b =====
    #pragma unroll
    for (int gi = 0; gi < 4; ++gi) acc[gi] = (f32x4){bL2[gi], bL2[gi], bL2[gi], bL2[gi]};
    #pragma unroll
    for (int kc = 0; kc < 2; ++kc) {
      short8 a = *reinterpret_cast<const short8*>(&h1s[pw][hr[kc]]);
      #pragma unroll
      for (int gi = 0; gi < 4; ++gi) {
        short8 b = *reinterpret_cast<const short8*>(&Wpih2[((kc * 16 + gi * 4 + q) * 64 + lane) * 8]);
        acc[gi] = __builtin_amdgcn_mfma_f32_16x16x32_bf16(a, b, acc[gi], 0, 0, 0);
      }
    }
    if (step > 0) {
      #pragma unroll
      for (int kc = 0; kc < 2; ++kc) {
        short8 a = *reinterpret_cast<const short8*>(&h2s[pr][hr[kc]]);
        #pragma unroll
        for (int gi = 0; gi < 4; ++gi) {
          short8 b = *reinterpret_cast<const short8*>(&Wphh2[((kc * 16 + gi * 4 + q) * 64 + lane) * 8]);
          acc[gi] = __builtin_amdgcn_mfma_f32_16x16x32_bf16(a, b, acc[gi], 0, 0, 0);
        }
      }
    }
    #pragma unroll
    for (int jr = 0; jr < 4; ++jr) {
      float gi_ = acc[0][jr], gf = acc[1][jr], gg = acc[2][jr], go = acc[3][jr];
      float cc = sigf(gf) * c2[jr] + sigf(gi_) * tanhf_(gg);
      c2[jr] = cc;
      float h = sigf(go) * tanhf_(cc);
      h2s[pw][hw[jr]] = f2bf(h);
      if (step == TWIN - 1) {
        int r = g * 4 + jr, j = q * 16 + c;
        out[(size_t)(tile * 16 + r) * OUTC + HD + j] = h;
      }
    }
    __syncthreads();
  }

  // folded skip connection S -> out cols 128..141 for this tile's 16 nodes
  for (int idx = t; idx < 16 * 14; idx += 256) {
    int r = idx / 14, cc = idx - r * 14;
    int n = tile * 16 + r;
    float v = (cc < CIN) ? x[(size_t)n * CIN + cc]
                         : x[((size_t)(cc - (CIN - 1)) * NODES + n) * CIN + (CIN - 1)];
    out[(size_t)n * OUTC + 128 + cc] = v;
  }
}

extern "C" void kernel_launch(void* const* d_in, const int* in_sizes, int n_in,
                              void* d_out, int out_size, void* d_ws, size_t ws_size,
                              hipStream_t stream) {
  const float* x      = (const float*)d_in[0];
  const int*   ei     = (const int*)d_in[1];
  const float* ew     = (const float*)d_in[2];
  const float* W1     = (const float*)d_in[3];
  const float* b1     = (const float*)d_in[4];
  const float* W2     = (const float*)d_in[5];
  const float* b2     = (const float*)d_in[6];
  const float* gamma1 = (const float*)d_in[7];
  const float* beta1  = (const float*)d_in[8];
  const float* gamma2 = (const float*)d_in[9];
  const float* beta2  = (const float*)d_in[10];
  const float* Wih1   = (const float*)d_in[11];
  const float* Whh1   = (const float*)d_in[12];
  const float* bih1   = (const float*)d_in[13];
  const float* bhh1   = (const float*)d_in[14];
  const float* Wih2   = (const float*)d_in[15];
  const float* Whh2   = (const float*)d_in[16];
  const float* bih2   = (const float*)d_in[17];
  const float* bhh2   = (const float*)d_in[18];
  const int* srcI = ei;
  const int* dstI = ei + NE;
  float* out = (float*)d_out;

  char* base = (char*)d_ws;
  size_t off = 0;
  auto alloc = [&](size_t bytes) -> void* {
    void* p = base + off;
    off = (off + bytes + 255) & ~(size_t)255;
    return p;
  };
  // small
  float* dinv   = (float*)alloc(N_TOT * 4);
  ushort* xs    = (ushort*)alloc((size_t)N_TOT * CIN * 2);   // dinv*x, bf16
  ushort* Wp1   = (ushort*)alloc(32768 * 2);
  ushort* Wphh1 = (ushort*)alloc(16384 * 2);
  ushort* Wpih2 = (ushort*)alloc(16384 * 2);
  ushort* Wphh2 = (ushort*)alloc(16384 * 2);
  ushort* Wp2   = (ushort*)alloc(4096 * 2);
  float* c2b    = (float*)alloc(HD * 4);
  float* biasL1 = (float*)alloc(256 * 4);
  float* bsum2  = (float*)alloc(256 * 4);
  float* scale1 = (float*)alloc(HD * 4);
  float* shift1 = (float*)alloc(HD * 4);
  float* scale2 = (float*)alloc(HD * 4);
  float* shift2 = (float*)alloc(HD * 4);
  // zeroed-every-call region (contiguous)
  char* zstart = base + off;
  int*   cursor = (int*)alloc(N_TOT * 4);
  float* sum1   = (float*)alloc(HD * 4);
  float* sq1    = (float*)alloc(HD * 4);
  float* sum2   = (float*)alloc(HD * 4);
  float* sq2    = (float*)alloc(HD * 4);
  size_t zbytes = (size_t)((base + off) - zstart);
  // big buffers (~125 MB)
  int2*   csr = (int2*)alloc((size_t)N_TOT * SLOTS * 8);   // 71.68 MB
  ushort* Hbs = (ushort*)alloc((size_t)N_TOT * HD * 2);
  ushort* A1  = (ushort*)alloc((size_t)N_TOT * HD * 2);
  ushort* A2  = (ushort*)alloc((size_t)N_TOT * HD * 2);

  hipMemsetAsync(zstart, 0, zbytes, stream);
  k_wpack0<<<193, 256, 0, stream>>>(Whh1, Wih2, Whh2, bih2, bhh2,
                                    Wphh1, Wpih2, Wphh2, bsum2);
  k_fill_direct<<<(NE + 255) / 256, 256, 0, stream>>>(srcI, dstI, ew, cursor, csr);
  k_prep2<<<1024, 256, 0, stream>>>(cursor, csr, x, dinv, xs);
  k_gcn1<<<1024, 256, 0, stream>>>(xs, dinv, cursor, csr, W1, b1, A1, sum1, sq1);
  k_bnfin<<<1, 64, 0, stream>>>(sum1, sq1, gamma1, beta1, scale1, shift1);
  k_mid1<<<17, 256, 0, stream>>>(W2, scale1, shift1, Wp2, c2b);
  k_gemm_h2<<<(HTILES + 3) / 4, 256, 0, stream>>>(A1, Wp2, c2b, dinv, Hbs);
  k_spmm2<<<1024, 256, 0, stream>>>(Hbs, dinv, cursor, csr, b2, A2, sum2, sq2);
  k_bnfin<<<1, 64, 0, stream>>>(sum2, sq2, gamma2, beta2, scale2, shift2);
  k_mid2<<<129, 256, 0, stream>>>(Wih1, scale1, scale2, shift1, shift2,
                                  bih1, bhh1, Wp1, biasL1);
  k_lstm5<<<NTILES, 256, 0, stream>>>(A1, A2, Wp1, Wphh1, Wpih2, Wphh2,
                                      biasL1, bsum2, x, out);
}